// Round 13
// baseline (132.061 us; speedup 1.0000x reference)
//
#include <hip/hip_runtime.h>

#define Bn 16
#define Sn 128
#define Hn 256
#define NLn 22
#define NSn 122

#define K2c 2.8853900817779268f   // 2*log2(e)
#define L2Ec 1.4426950408889634f  // log2(e)

__device__ __forceinline__ float fexp2(float x) { return __builtin_amdgcn_exp2f(x); }
__device__ __forceinline__ float frcp(float x) { return __builtin_amdgcn_rcpf(x); }

union F4 { float4 v; float f[4]; };

// ---------------------------------------------------------------------------
// A-update body: rL -> m -> em -> f -> g2.  1024 threads = h(256) x kq(4).
// coh=1: read alphas with agent-scope atomic loads (same-launch producers).
// ---------------------------------------------------------------------------
__device__ __forceinline__ void A_body(const float* __restrict__ c_slot,
                                       const float* __restrict__ c_inte,
                                       const float* __restrict__ W_SF,
                                       const float* __restrict__ V_SF,
                                       const float* alphas,
                                       float* __restrict__ g2,
                                       int b, int use_alpha, int coh,
                                       float* rL, float* fLq, float* aL,
                                       float (*pt)[Hn]) {
  const int tid = threadIdx.x;
  const int h = tid & (Hn - 1);
  const int kq = tid >> 8;

  if (use_alpha) {
    if (tid < Sn)
      aL[tid] = coh ? __hip_atomic_load(&alphas[b * Sn + tid],
                                        __ATOMIC_RELAXED, __HIP_MEMORY_SCOPE_AGENT)
                    : alphas[b * Sn + tid];
    __syncthreads();
    float ps = 0.f;
    #pragma unroll 8
    for (int s = kq * 32; s < kq * 32 + 32; ++s)
      ps += c_slot[(size_t)(b * Sn + s) * Hn + h] * aL[s];
    pt[kq][h] = ps;
    __syncthreads();
    if (!kq)
      rL[h] = c_inte[b * Hn + h] +
              g2[b * Hn + h] * (pt[0][h] + pt[1][h] + pt[2][h] + pt[3][h]);
  } else {
    if (!kq) rL[h] = c_inte[b * Hn + h];
  }
  __syncthreads();

  // m = rL @ W_SF (4-way k-split)
  float pm = 0.f;
  #pragma unroll 8
  for (int k = kq * 64; k < kq * 64 + 64; ++k)
    pm += rL[k] * W_SF[(size_t)k * Hn + h];
  __syncthreads();               // protect pt from rs-phase reads
  pt[kq][h] = pm;
  __syncthreads();
  const float m = pt[0][h] + pt[1][h] + pt[2][h] + pt[3][h];
  const float em = fexp2(fminf(fmaxf(K2c * m, -60.f), 60.f));

  // f partial: 32 s per kq
  float pr = 0.f;
  #pragma unroll 8
  for (int s = kq * 32; s < kq * 32 + 32; ++s) {
    float zc = fminf(fmaxf(K2c * c_slot[(size_t)(b * Sn + s) * Hn + h], -60.f), 60.f);
    pr += frcp(fmaf(fexp2(zc), em, 1.f));
  }
  __syncthreads();               // all m-reads of pt complete
  pt[kq][h] = pr;
  __syncthreads();
  if (!kq) fLq[h] = (float)Sn - 2.f * (pt[0][h] + pt[1][h] + pt[2][h] + pt[3][h]);
  __syncthreads();

  // g2 = fLq @ V_SF (4-way k-split)
  float pg = 0.f;
  #pragma unroll 8
  for (int k = kq * 64; k < kq * 64 + 64; ++k)
    pg += fLq[k] * V_SF[(size_t)k * Hn + h];
  __syncthreads();
  pt[kq][h] = pg;
  __syncthreads();
  if (!kq)
    g2[b * Hn + h] = pt[0][h] + pt[1][h] + pt[2][h] + pt[3][h];
}

// ---------------------------------------------------------------------------
// k_hfA: blocks 0..255: hf -> ZT (8 rows each, j-contiguous exp2(K2*hf)).
//        blocks 256..271: A-update for iteration 0 (no alphas) -> g2.
// ---------------------------------------------------------------------------
__global__ __launch_bounds__(1024) void k_hfA(const float* __restrict__ hp,
                                              const float* __restrict__ V2w,
                                              const float* __restrict__ V2b,
                                              const float* __restrict__ c_slot,
                                              const float* __restrict__ c_inte,
                                              const float* __restrict__ W_SF,
                                              const float* __restrict__ V_SF,
                                              float* __restrict__ ZT,
                                              float* __restrict__ g2) {
  __shared__ float xT[Hn][8];
  __shared__ float pp[3][Hn][8];
  __shared__ float rL[Hn];
  __shared__ float fLq[Hn];
  __shared__ float aL[Sn];
  __shared__ float pt[4][Hn];
  const int tid = threadIdx.x;
  const int blk = blockIdx.x;

  if (blk >= 256) {              // A-update, iteration 0
    A_body(c_slot, c_inte, W_SF, V_SF, nullptr, g2, blk - 256, 0, 0,
           rL, fLq, aL, pt);
    return;
  }

  const int r0 = blk * 8;
  const int b = r0 >> 7;
  const int j0 = r0 & (Sn - 1);
  const int h = tid & (Hn - 1);
  const int kh = tid >> 8;       // 0..3
  xT[h][kh * 2]     = hp[(size_t)(r0 + kh * 2) * Hn + h];
  xT[h][kh * 2 + 1] = hp[(size_t)(r0 + kh * 2 + 1) * Hn + h];
  __syncthreads();
  float acc[8] = {0.f, 0.f, 0.f, 0.f, 0.f, 0.f, 0.f, 0.f};
  #pragma unroll 8
  for (int k = kh * 64; k < kh * 64 + 64; ++k) {
    const float v = V2w[(size_t)k * Hn + h];
    F4 xa, xb;
    xa.v = *(const float4*)&xT[k][0];
    xb.v = *(const float4*)&xT[k][4];
    acc[0] += xa.f[0] * v; acc[1] += xa.f[1] * v;
    acc[2] += xa.f[2] * v; acc[3] += xa.f[3] * v;
    acc[4] += xb.f[0] * v; acc[5] += xb.f[1] * v;
    acc[6] += xb.f[2] * v; acc[7] += xb.f[3] * v;
  }
  if (kh) {
    F4 s0, s1;
    s0.f[0] = acc[0]; s0.f[1] = acc[1]; s0.f[2] = acc[2]; s0.f[3] = acc[3];
    s1.f[0] = acc[4]; s1.f[1] = acc[5]; s1.f[2] = acc[6]; s1.f[3] = acc[7];
    *(float4*)&pp[kh - 1][h][0] = s0.v;
    *(float4*)&pp[kh - 1][h][4] = s1.v;
  }
  __syncthreads();
  if (!kh) {
    const float bj = V2b[h];
    F4 o0, o1;
    #pragma unroll
    for (int i = 0; i < 8; ++i) {
      float z = K2c * (acc[i] + pp[0][h][i] + pp[1][h][i] + pp[2][h][i] + bj);
      z = fminf(fmaxf(z, -60.f), 60.f);
      if (i < 4) o0.f[i] = fexp2(z); else o1.f[i - 4] = fexp2(z);
    }
    *(float4*)&ZT[((size_t)b * Hn + h) * Sn + j0] = o0.v;
    *(float4*)&ZT[((size_t)b * Hn + h) * Sn + j0 + 4] = o1.v;
  }
}

// ---------------------------------------------------------------------------
// k_C: 512 blocks = (b, 4-row group), 1024 threads, ~25KB LDS.
// Scores -> alphas (agent-scope stores). If do_tail: per-b counter; the
// 32nd-finishing block of b runs the NEXT iteration's A-update in its tail
// (reads all alphas of b via agent loads, writes g2 for the next launch).
// ---------------------------------------------------------------------------
__global__ __launch_bounds__(1024) void k_C(const float* __restrict__ c_slot,
                                            const float* __restrict__ V1,
                                            float* __restrict__ g2,
                                            const float* __restrict__ ZT,
                                            const float* __restrict__ wid,
                                            float* alphas,
                                            const float* __restrict__ c_inte,
                                            const float* __restrict__ W_SF,
                                            const float* __restrict__ V_SF,
                                            unsigned* cnt, int do_tail) {
  __shared__ float bufA[Hn][4];    // xT
  __shared__ float bufB[Hn][4];    // YT
  __shared__ union {
    float pp[3][Hn][4];            // phase2 partials (12KB)
    float red[7][4][Sn];           // phase3 partials (14KB)
    struct { float rL[Hn]; float fLq[Hn]; float aL[Sn]; float pt[4][Hn]; } a;
  } u;
  __shared__ float sc4[4][Sn];
  __shared__ float wL[Hn];
  __shared__ int lastFlag;

  const int tid = threadIdx.x;
  const int blk = blockIdx.x;
  const int b = blk >> 5;
  const int i0 = (blk & 31) * 4;
  const int h = tid & (Hn - 1);
  const int kq = tid >> 8;         // 0..3

  // phase1
  bufA[h][kq] = g2[b * Hn + h] * c_slot[(size_t)(b * Sn + i0 + kq) * Hn + h];
  if (tid < Hn) wL[tid] = wid[tid];
  __syncthreads();

  // phase2: sf = x @ V1 (4-way kq split) -> Y
  {
    float acc[4] = {0.f, 0.f, 0.f, 0.f};
    #pragma unroll 8
    for (int k = kq * 64; k < kq * 64 + 64; ++k) {
      const float v = V1[(size_t)k * Hn + h];
      F4 xa; xa.v = *(const float4*)&bufA[k][0];
      acc[0] += xa.f[0] * v; acc[1] += xa.f[1] * v;
      acc[2] += xa.f[2] * v; acc[3] += xa.f[3] * v;
    }
    if (kq) {
      F4 s0;
      s0.f[0] = acc[0]; s0.f[1] = acc[1]; s0.f[2] = acc[2]; s0.f[3] = acc[3];
      *(float4*)&u.pp[kq - 1][h][0] = s0.v;
    }
    __syncthreads();
    if (!kq) {
      #pragma unroll
      for (int i = 0; i < 4; ++i) {
        float z = K2c * (acc[i] + u.pp[0][h][i] + u.pp[1][h][i] + u.pp[2][h][i]);
        z = fminf(fmaxf(z, -60.f), 60.f);
        bufB[h][i] = fexp2(z);
      }
    }
  }
  __syncthreads();

  // phase3: inline coalesced ZT loads (lane = j), 32 hh per thread
  const int j = tid & (Sn - 1);
  const int hq = tid >> 7;         // 0..7
  float a4[4] = {0.f, 0.f, 0.f, 0.f};
  const float* zp = ZT + ((size_t)b * Hn + hq * 32) * Sn + j;
  #pragma unroll 4
  for (int hh = 0; hh < 32; ++hh) {
    const float z = zp[(size_t)hh * Sn];
    const float wh = wL[hq * 32 + hh];
    F4 ya; ya.v = *(const float4*)&bufB[hq * 32 + hh][0];
    a4[0] += wh * frcp(fmaf(ya.f[0], z, 1.f));
    a4[1] += wh * frcp(fmaf(ya.f[1], z, 1.f));
    a4[2] += wh * frcp(fmaf(ya.f[2], z, 1.f));
    a4[3] += wh * frcp(fmaf(ya.f[3], z, 1.f));
  }
  if (hq) {
    #pragma unroll
    for (int i = 0; i < 4; ++i) u.red[hq - 1][i][j] = a4[i];
  }
  __syncthreads();
  if (!hq) {
    #pragma unroll
    for (int i = 0; i < 4; ++i) {
      float tot = a4[i];
      #pragma unroll
      for (int r = 0; r < 7; ++r) tot += u.red[r][i][j];
      sc4[i][j] = -2.f * L2Ec * tot;   // log2-domain score (const dropped)
    }
  }
  __syncthreads();

  // phase4: softmax, 4 rows x 32 lanes; agent-scope alpha stores
  if (tid < 128) {
    const int row = tid >> 5;
    const int l5 = tid & 31;
    const float v0 = sc4[row][l5];
    const float v1 = sc4[row][l5 + 32];
    const float v2 = sc4[row][l5 + 64];
    const float v3 = sc4[row][l5 + 96];
    float mx = fmaxf(fmaxf(v0, v1), fmaxf(v2, v3));
    #pragma unroll
    for (int o = 16; o >= 1; o >>= 1) mx = fmaxf(mx, __shfl_xor(mx, o, 32));
    float sm = fexp2(v0 - mx) + fexp2(v1 - mx) + fexp2(v2 - mx) + fexp2(v3 - mx);
    #pragma unroll
    for (int o = 16; o >= 1; o >>= 1) sm += __shfl_xor(sm, o, 32);
    if (l5 == 0) {
      const int ig = i0 + row;
      const float av = fexp2(sc4[row][ig] - mx) * frcp(sm);
      __hip_atomic_store(&alphas[b * Sn + ig], av,
                         __ATOMIC_RELAXED, __HIP_MEMORY_SCOPE_AGENT);
    }
  }

  if (!do_tail) return;

  // ---- tail: 32nd finisher of b runs next iteration's A-update ----
  __syncthreads();               // drains all vmem (incl. alpha stores)
  if (tid == 0) {
    unsigned old = __hip_atomic_fetch_add(&cnt[b], 1u, __ATOMIC_ACQ_REL,
                                          __HIP_MEMORY_SCOPE_AGENT);
    lastFlag = (old == 31u);
  }
  __syncthreads();
  if (!lastFlag) return;
  A_body(c_slot, c_inte, W_SF, V_SF, alphas, g2, b, 1, 1,
         u.a.rL, u.a.fLq, u.a.aL, u.a.pt);
}

// ---------------------------------------------------------------------------
// k_out: 256 blocks x 512. All blocks: slot head (8 rows). Blocks 0..15 also
// do the intent head afterwards (disjoint LDS arrays).
// ---------------------------------------------------------------------------
__global__ __launch_bounds__(512) void k_out(const float* __restrict__ hp,
                                             const float* __restrict__ c_slot,
                                             const float* __restrict__ c_inte,
                                             const float* __restrict__ g2,
                                             const float* __restrict__ alphas,
                                             const float* __restrict__ Wi,
                                             const float* __restrict__ Ws,
                                             float* __restrict__ outS,
                                             float* __restrict__ outI) {
  __shared__ float bufA[Hn][8];
  __shared__ float bufB[Hn][8];
  __shared__ float red[3][8][Sn];
  __shared__ float aL[Sn];
  __shared__ float cv[2 * Hn];
  __shared__ float ptA[2][Hn];
  __shared__ float ip[NLn][16];
  const int tid = threadIdx.x;
  const int blk = blockIdx.x;
  const int r0 = blk * 8;
  const int b2 = r0 >> 7;

  if (tid < Hn) {
    #pragma unroll
    for (int i = 0; i < 8; ++i) bufA[tid][i] = hp[(size_t)(r0 + i) * Hn + tid];
  } else {
    const int t = tid - Hn;
    const float gv = g2[b2 * Hn + t];
    #pragma unroll
    for (int i = 0; i < 8; ++i)
      bufB[t][i] = gv * c_slot[(size_t)(r0 + i) * Hn + t];
  }
  __syncthreads();
  const int jc = tid & 127;
  const int kq = tid >> 7;
  float acc[8] = {0.f, 0.f, 0.f, 0.f, 0.f, 0.f, 0.f, 0.f};
  if (jc < NSn) {
    const float (*xb)[8] = (kq < 2) ? bufA : bufB;
    const int kg0 = kq * 128;
    const int koff = (kq < 2) ? kg0 : kg0 - 256;
    #pragma unroll 8
    for (int u = 0; u < 128; ++u) {
      const float v = Ws[(size_t)(kg0 + u) * NSn + jc];
      F4 xa, xb4;
      xa.v = *(const float4*)&xb[koff + u][0];
      xb4.v = *(const float4*)&xb[koff + u][4];
      acc[0] += xa.f[0] * v; acc[1] += xa.f[1] * v;
      acc[2] += xa.f[2] * v; acc[3] += xa.f[3] * v;
      acc[4] += xb4.f[0] * v; acc[5] += xb4.f[1] * v;
      acc[6] += xb4.f[2] * v; acc[7] += xb4.f[3] * v;
    }
  }
  if (kq) {
    #pragma unroll
    for (int i = 0; i < 8; ++i) red[kq - 1][i][jc] = acc[i];
  }
  __syncthreads();
  if (!kq && jc < NSn) {
    #pragma unroll
    for (int i = 0; i < 8; ++i)
      outS[(size_t)(r0 + i) * NSn + jc] =
          acc[i] + red[0][i][jc] + red[1][i][jc] + red[2][i][jc];
  }

  // intent head on blocks 0..15
  if (blk < Bn) {
    const int b = blk;
    if (tid < Sn) aL[tid] = alphas[b * Sn + tid];
    __syncthreads();
    const int h = tid & (Hn - 1);
    const int k2 = tid >> 8;
    float ps = 0.f;
    #pragma unroll 8
    for (int s = k2 * 64; s < k2 * 64 + 64; ++s)
      ps += c_slot[(size_t)(b * Sn + s) * Hn + h] * aL[s];
    ptA[k2][h] = ps;
    __syncthreads();
    if (!k2) {
      cv[h] = c_inte[b * Hn + h] + g2[b * Hn + h] * (ptA[0][h] + ptA[1][h]);
      cv[Hn + h] = hp[(size_t)(b * Sn + Sn - 1) * Hn + h];
    }
    __syncthreads();
    if (tid < NLn * 16) {
      const int l = tid >> 4, c = tid & 15;
      float p = 0.f;
      #pragma unroll
      for (int k = c * 32; k < c * 32 + 32; ++k) p += cv[k] * Wi[k * NLn + l];
      ip[l][c] = p;
    }
    __syncthreads();
    if (tid < NLn) {
      float t = 0.f;
      #pragma unroll
      for (int c = 0; c < 16; ++c) t += ip[tid][c];
      outI[b * NLn + tid] = t;
    }
  }
}

// ---------------------------------------------------------------------------
extern "C" void kernel_launch(void* const* d_in, const int* in_sizes, int n_in,
                              void* d_out, int out_size, void* d_ws, size_t ws_size,
                              hipStream_t stream) {
  const float* hp     = (const float*)d_in[0];
  const float* c_slot = (const float*)d_in[1];
  const float* c_inte = (const float*)d_in[2];
  const float* W_SF   = (const float*)d_in[3];
  const float* V_SF   = (const float*)d_in[4];
  const float* V1     = (const float*)d_in[5];
  const float* V2w    = (const float*)d_in[6];
  const float* V2b    = (const float*)d_in[7];
  const float* wid    = (const float*)d_in[8];
  const float* Wi     = (const float*)d_in[9];
  const float* Ws     = (const float*)d_in[10];
  float* outS = (float*)d_out;                   // B*S*NS
  float* outI = (float*)d_out + Bn * Sn * NSn;   // B*NL

  float* ws = (float*)d_ws;
  float* ZT      = ws;                       // B*H*S (j-contig)
  float* g2      = ZT + (size_t)Bn * Sn * Hn;
  float* alphas  = g2 + Bn * Hn;
  unsigned* cnt  = (unsigned*)(alphas + Bn * Sn);  // 2 x 16 counters

  hipMemsetAsync(cnt, 0, 2 * Bn * sizeof(unsigned), stream);
  // hf + A(it=0) fused
  hipLaunchKernelGGL(k_hfA, dim3(256 + Bn), dim3(1024), 0, stream,
                     hp, V2w, V2b, c_slot, c_inte, W_SF, V_SF, ZT, g2);
  // C0: scores it0 + tail A(it1);  C1: scores it1 + tail A(it2);  C2: scores it2
  hipLaunchKernelGGL(k_C, dim3(512), dim3(1024), 0, stream,
                     c_slot, V1, g2, ZT, wid, alphas, c_inte, W_SF, V_SF,
                     cnt, 1);
  hipLaunchKernelGGL(k_C, dim3(512), dim3(1024), 0, stream,
                     c_slot, V1, g2, ZT, wid, alphas, c_inte, W_SF, V_SF,
                     cnt + Bn, 1);
  hipLaunchKernelGGL(k_C, dim3(512), dim3(1024), 0, stream,
                     c_slot, V1, g2, ZT, wid, alphas, c_inte, W_SF, V_SF,
                     nullptr, 0);
  hipLaunchKernelGGL(k_out, dim3(Bn * Sn / 8), dim3(512), 0, stream,
                     hp, c_slot, c_inte, g2, alphas, Wi, Ws, outS, outI);
}

// Round 14
// 113.804 us; speedup vs baseline: 1.1604x; 1.1604x over previous
//
#include <hip/hip_runtime.h>

#define Bn 16
#define Sn 128
#define Hn 256
#define NLn 22
#define NSn 122

#define K2c 2.8853900817779268f   // 2*log2(e)
#define L2Ec 1.4426950408889634f  // log2(e)

__device__ __forceinline__ float fexp2(float x) { return __builtin_amdgcn_exp2f(x); }
__device__ __forceinline__ float frcp(float x) { return __builtin_amdgcn_rcpf(x); }

union F4 { float4 v; float f[4]; };

// ---------------------------------------------------------------------------
// A-update body: rL -> m -> em -> f -> g2.  1024 threads = h(256) x kq(4).
// Writes g2[b][h] directly.  use_alpha=0 for iteration 0.
// ---------------------------------------------------------------------------
__device__ __forceinline__ void A_body(const float* __restrict__ c_slot,
                                       const float* __restrict__ c_inte,
                                       const float* __restrict__ W_SF,
                                       const float* __restrict__ V_SF,
                                       const float* __restrict__ alphas,
                                       float* __restrict__ g2,
                                       int b, int use_alpha,
                                       float* rL, float* fLq, float* aL,
                                       float (*pt)[Hn]) {
  const int tid = threadIdx.x;
  const int h = tid & (Hn - 1);
  const int kq = tid >> 8;

  if (use_alpha) {
    if (tid < Sn) aL[tid] = alphas[b * Sn + tid];
    __syncthreads();
    float ps = 0.f;
    #pragma unroll 8
    for (int s = kq * 32; s < kq * 32 + 32; ++s)
      ps += c_slot[(size_t)(b * Sn + s) * Hn + h] * aL[s];
    pt[kq][h] = ps;
    __syncthreads();
    if (!kq)
      rL[h] = c_inte[b * Hn + h] +
              g2[b * Hn + h] * (pt[0][h] + pt[1][h] + pt[2][h] + pt[3][h]);
  } else {
    if (!kq) rL[h] = c_inte[b * Hn + h];
  }
  __syncthreads();

  // m = rL @ W_SF (4-way k-split)
  float pm = 0.f;
  #pragma unroll 8
  for (int k = kq * 64; k < kq * 64 + 64; ++k)
    pm += rL[k] * W_SF[(size_t)k * Hn + h];
  __syncthreads();               // protect pt from rs-phase reads
  pt[kq][h] = pm;
  __syncthreads();
  const float m = pt[0][h] + pt[1][h] + pt[2][h] + pt[3][h];
  const float em = fexp2(fminf(fmaxf(K2c * m, -60.f), 60.f));

  // f partial: 32 s per kq
  float pr = 0.f;
  #pragma unroll 8
  for (int s = kq * 32; s < kq * 32 + 32; ++s) {
    float zc = fminf(fmaxf(K2c * c_slot[(size_t)(b * Sn + s) * Hn + h], -60.f), 60.f);
    pr += frcp(fmaf(fexp2(zc), em, 1.f));
  }
  __syncthreads();               // all m-reads of pt complete
  pt[kq][h] = pr;
  __syncthreads();
  if (!kq) fLq[h] = (float)Sn - 2.f * (pt[0][h] + pt[1][h] + pt[2][h] + pt[3][h]);
  __syncthreads();

  // g2 = fLq @ V_SF (4-way k-split)
  float pg = 0.f;
  #pragma unroll 8
  for (int k = kq * 64; k < kq * 64 + 64; ++k)
    pg += fLq[k] * V_SF[(size_t)k * Hn + h];
  __syncthreads();
  pt[kq][h] = pg;
  __syncthreads();
  if (!kq)
    g2[b * Hn + h] = pt[0][h] + pt[1][h] + pt[2][h] + pt[3][h];
}

// ---------------------------------------------------------------------------
// k_hfA: blocks 0..255: hf -> ZT (8 rows each, j-contiguous exp2(K2*hf)).
//        blocks 256..271: A-update for iteration 0 (no alphas) -> g2.
// ---------------------------------------------------------------------------
__global__ __launch_bounds__(1024) void k_hfA(const float* __restrict__ hp,
                                              const float* __restrict__ V2w,
                                              const float* __restrict__ V2b,
                                              const float* __restrict__ c_slot,
                                              const float* __restrict__ c_inte,
                                              const float* __restrict__ W_SF,
                                              const float* __restrict__ V_SF,
                                              float* __restrict__ ZT,
                                              float* __restrict__ g2) {
  __shared__ float xT[Hn][8];
  __shared__ float pp[3][Hn][8];
  __shared__ float rL[Hn];
  __shared__ float fLq[Hn];
  __shared__ float aL[Sn];
  __shared__ float pt[4][Hn];
  const int tid = threadIdx.x;
  const int blk = blockIdx.x;

  if (blk >= 256) {              // A-update, iteration 0
    A_body(c_slot, c_inte, W_SF, V_SF, nullptr, g2, blk - 256, 0,
           rL, fLq, aL, pt);
    return;
  }

  const int r0 = blk * 8;
  const int b = r0 >> 7;
  const int j0 = r0 & (Sn - 1);
  const int h = tid & (Hn - 1);
  const int kh = tid >> 8;       // 0..3
  xT[h][kh * 2]     = hp[(size_t)(r0 + kh * 2) * Hn + h];
  xT[h][kh * 2 + 1] = hp[(size_t)(r0 + kh * 2 + 1) * Hn + h];
  __syncthreads();
  float acc[8] = {0.f, 0.f, 0.f, 0.f, 0.f, 0.f, 0.f, 0.f};
  #pragma unroll 8
  for (int k = kh * 64; k < kh * 64 + 64; ++k) {
    const float v = V2w[(size_t)k * Hn + h];
    F4 xa, xb;
    xa.v = *(const float4*)&xT[k][0];
    xb.v = *(const float4*)&xT[k][4];
    acc[0] += xa.f[0] * v; acc[1] += xa.f[1] * v;
    acc[2] += xa.f[2] * v; acc[3] += xa.f[3] * v;
    acc[4] += xb.f[0] * v; acc[5] += xb.f[1] * v;
    acc[6] += xb.f[2] * v; acc[7] += xb.f[3] * v;
  }
  if (kh) {
    F4 s0, s1;
    s0.f[0] = acc[0]; s0.f[1] = acc[1]; s0.f[2] = acc[2]; s0.f[3] = acc[3];
    s1.f[0] = acc[4]; s1.f[1] = acc[5]; s1.f[2] = acc[6]; s1.f[3] = acc[7];
    *(float4*)&pp[kh - 1][h][0] = s0.v;
    *(float4*)&pp[kh - 1][h][4] = s1.v;
  }
  __syncthreads();
  if (!kh) {
    const float bj = V2b[h];
    F4 o0, o1;
    #pragma unroll
    for (int i = 0; i < 8; ++i) {
      float z = K2c * (acc[i] + pp[0][h][i] + pp[1][h][i] + pp[2][h][i] + bj);
      z = fminf(fmaxf(z, -60.f), 60.f);
      if (i < 4) o0.f[i] = fexp2(z); else o1.f[i - 4] = fexp2(z);
    }
    *(float4*)&ZT[((size_t)b * Hn + h) * Sn + j0] = o0.v;
    *(float4*)&ZT[((size_t)b * Hn + h) * Sn + j0 + 4] = o1.v;
  }
}

// ---------------------------------------------------------------------------
// k_A: iterations 1,2. 16 blocks (one per b) x 1024 threads. Writes g2.
// ---------------------------------------------------------------------------
__global__ __launch_bounds__(1024) void k_A(const float* __restrict__ c_slot,
                                            const float* __restrict__ c_inte,
                                            const float* __restrict__ W_SF,
                                            const float* __restrict__ V_SF,
                                            const float* __restrict__ alphas,
                                            float* __restrict__ g2) {
  __shared__ float rL[Hn];
  __shared__ float fLq[Hn];
  __shared__ float aL[Sn];
  __shared__ float pt[4][Hn];
  A_body(c_slot, c_inte, W_SF, V_SF, alphas, g2, blockIdx.x, 1,
         rL, fLq, aL, pt);
}

// ---------------------------------------------------------------------------
// k_C: scores. 512 blocks = (b, 4-row group), 1024 threads, ~25KB LDS.
// LDS tiles TRANSPOSED to [4][Hn] (lane-contiguous writes, zero bank
// conflicts; reads are b32 broadcasts). 16-deep ZT register prefetch issued
// at entry hides half of phase3's L2 latency under phases 1-2.
// ---------------------------------------------------------------------------
__global__ __launch_bounds__(1024) void k_C(const float* __restrict__ c_slot,
                                            const float* __restrict__ V1,
                                            const float* __restrict__ g2,
                                            const float* __restrict__ ZT,
                                            const float* __restrict__ wid,
                                            float* __restrict__ alphas) {
  __shared__ float bufA[4][Hn];    // xT (transposed)
  __shared__ float bufB[4][Hn];    // YT (transposed)
  __shared__ union {
    float pp[3][4][Hn];            // phase2 partials (12KB)
    float red[7][4][Sn];           // phase3 partials (14KB)
  } u;
  __shared__ float sc4[4][Sn];
  __shared__ float wL[Hn];

  const int tid = threadIdx.x;
  const int blk = blockIdx.x;
  const int b = blk >> 5;
  const int i0 = (blk & 31) * 4;
  const int h = tid & (Hn - 1);
  const int kq = tid >> 8;         // 0..3
  const int j = tid & (Sn - 1);
  const int hq = tid >> 7;         // 0..7

  // entry: prefetch first 16 ZT values for phase3 (hidden under P1/P2)
  const float* zp = ZT + ((size_t)b * Hn + hq * 32) * Sn + j;
  float zv[16];
  #pragma unroll
  for (int t = 0; t < 16; ++t) zv[t] = zp[(size_t)t * Sn];

  // phase1 (lane-contiguous LDS writes)
  bufA[kq][h] = g2[b * Hn + h] * c_slot[(size_t)(b * Sn + i0 + kq) * Hn + h];
  if (tid < Hn) wL[tid] = wid[tid];
  __syncthreads();

  // phase2: sf = x @ V1 (4-way kq split) -> Y
  {
    float acc[4] = {0.f, 0.f, 0.f, 0.f};
    #pragma unroll 8
    for (int k = kq * 64; k < kq * 64 + 64; ++k) {
      const float v = V1[(size_t)k * Hn + h];
      acc[0] += bufA[0][k] * v;
      acc[1] += bufA[1][k] * v;
      acc[2] += bufA[2][k] * v;
      acc[3] += bufA[3][k] * v;
    }
    if (kq) {
      #pragma unroll
      for (int i = 0; i < 4; ++i) u.pp[kq - 1][i][h] = acc[i];
    }
    __syncthreads();
    if (!kq) {
      #pragma unroll
      for (int i = 0; i < 4; ++i) {
        float z = K2c * (acc[i] + u.pp[0][i][h] + u.pp[1][i][h] + u.pp[2][i][h]);
        z = fminf(fmaxf(z, -60.f), 60.f);
        bufB[i][h] = fexp2(z);
      }
    }
  }
  __syncthreads();

  // phase3: 32 hh per thread; first 16 z from prefetch regs, rest inline
  float a4[4] = {0.f, 0.f, 0.f, 0.f};
  #pragma unroll
  for (int hh = 0; hh < 16; ++hh) {
    const float z = zv[hh];
    const float wh = wL[hq * 32 + hh];
    const int hx = hq * 32 + hh;
    a4[0] += wh * frcp(fmaf(bufB[0][hx], z, 1.f));
    a4[1] += wh * frcp(fmaf(bufB[1][hx], z, 1.f));
    a4[2] += wh * frcp(fmaf(bufB[2][hx], z, 1.f));
    a4[3] += wh * frcp(fmaf(bufB[3][hx], z, 1.f));
  }
  #pragma unroll 4
  for (int hh = 16; hh < 32; ++hh) {
    const float z = zp[(size_t)hh * Sn];
    const float wh = wL[hq * 32 + hh];
    const int hx = hq * 32 + hh;
    a4[0] += wh * frcp(fmaf(bufB[0][hx], z, 1.f));
    a4[1] += wh * frcp(fmaf(bufB[1][hx], z, 1.f));
    a4[2] += wh * frcp(fmaf(bufB[2][hx], z, 1.f));
    a4[3] += wh * frcp(fmaf(bufB[3][hx], z, 1.f));
  }
  if (hq) {
    #pragma unroll
    for (int i = 0; i < 4; ++i) u.red[hq - 1][i][j] = a4[i];
  }
  __syncthreads();
  if (!hq) {
    #pragma unroll
    for (int i = 0; i < 4; ++i) {
      float tot = a4[i];
      #pragma unroll
      for (int r = 0; r < 7; ++r) tot += u.red[r][i][j];
      sc4[i][j] = -2.f * L2Ec * tot;   // log2-domain score (const dropped)
    }
  }
  __syncthreads();

  // phase4: softmax, 4 rows x 32 lanes
  if (tid < 128) {
    const int row = tid >> 5;
    const int l5 = tid & 31;
    const float v0 = sc4[row][l5];
    const float v1 = sc4[row][l5 + 32];
    const float v2 = sc4[row][l5 + 64];
    const float v3 = sc4[row][l5 + 96];
    float mx = fmaxf(fmaxf(v0, v1), fmaxf(v2, v3));
    #pragma unroll
    for (int o = 16; o >= 1; o >>= 1) mx = fmaxf(mx, __shfl_xor(mx, o, 32));
    float sm = fexp2(v0 - mx) + fexp2(v1 - mx) + fexp2(v2 - mx) + fexp2(v3 - mx);
    #pragma unroll
    for (int o = 16; o >= 1; o >>= 1) sm += __shfl_xor(sm, o, 32);
    if (l5 == 0) {
      const int ig = i0 + row;
      alphas[b * Sn + ig] = fexp2(sc4[row][ig] - mx) * frcp(sm);
    }
  }
}

// ---------------------------------------------------------------------------
// k_out: 256 blocks x 512. All blocks: slot head (8 rows). Blocks 0..15 also
// do the intent head afterwards (disjoint LDS arrays).
// ---------------------------------------------------------------------------
__global__ __launch_bounds__(512) void k_out(const float* __restrict__ hp,
                                             const float* __restrict__ c_slot,
                                             const float* __restrict__ c_inte,
                                             const float* __restrict__ g2,
                                             const float* __restrict__ alphas,
                                             const float* __restrict__ Wi,
                                             const float* __restrict__ Ws,
                                             float* __restrict__ outS,
                                             float* __restrict__ outI) {
  __shared__ float bufA[Hn][8];
  __shared__ float bufB[Hn][8];
  __shared__ float red[3][8][Sn];
  __shared__ float aL[Sn];
  __shared__ float cv[2 * Hn];
  __shared__ float ptA[2][Hn];
  __shared__ float ip[NLn][16];
  const int tid = threadIdx.x;
  const int blk = blockIdx.x;
  const int r0 = blk * 8;
  const int b2 = r0 >> 7;

  if (tid < Hn) {
    #pragma unroll
    for (int i = 0; i < 8; ++i) bufA[tid][i] = hp[(size_t)(r0 + i) * Hn + tid];
  } else {
    const int t = tid - Hn;
    const float gv = g2[b2 * Hn + t];
    #pragma unroll
    for (int i = 0; i < 8; ++i)
      bufB[t][i] = gv * c_slot[(size_t)(r0 + i) * Hn + t];
  }
  __syncthreads();
  const int jc = tid & 127;
  const int kq = tid >> 7;
  float acc[8] = {0.f, 0.f, 0.f, 0.f, 0.f, 0.f, 0.f, 0.f};
  if (jc < NSn) {
    const float (*xb)[8] = (kq < 2) ? bufA : bufB;
    const int kg0 = kq * 128;
    const int koff = (kq < 2) ? kg0 : kg0 - 256;
    #pragma unroll 8
    for (int u = 0; u < 128; ++u) {
      const float v = Ws[(size_t)(kg0 + u) * NSn + jc];
      F4 xa, xb4;
      xa.v = *(const float4*)&xb[koff + u][0];
      xb4.v = *(const float4*)&xb[koff + u][4];
      acc[0] += xa.f[0] * v; acc[1] += xa.f[1] * v;
      acc[2] += xa.f[2] * v; acc[3] += xa.f[3] * v;
      acc[4] += xb4.f[0] * v; acc[5] += xb4.f[1] * v;
      acc[6] += xb4.f[2] * v; acc[7] += xb4.f[3] * v;
    }
  }
  if (kq) {
    #pragma unroll
    for (int i = 0; i < 8; ++i) red[kq - 1][i][jc] = acc[i];
  }
  __syncthreads();
  if (!kq && jc < NSn) {
    #pragma unroll
    for (int i = 0; i < 8; ++i)
      outS[(size_t)(r0 + i) * NSn + jc] =
          acc[i] + red[0][i][jc] + red[1][i][jc] + red[2][i][jc];
  }

  // intent head on blocks 0..15
  if (blk < Bn) {
    const int b = blk;
    if (tid < Sn) aL[tid] = alphas[b * Sn + tid];
    __syncthreads();
    const int h = tid & (Hn - 1);
    const int k2 = tid >> 8;
    float ps = 0.f;
    #pragma unroll 8
    for (int s = k2 * 64; s < k2 * 64 + 64; ++s)
      ps += c_slot[(size_t)(b * Sn + s) * Hn + h] * aL[s];
    ptA[k2][h] = ps;
    __syncthreads();
    if (!k2) {
      cv[h] = c_inte[b * Hn + h] + g2[b * Hn + h] * (ptA[0][h] + ptA[1][h]);
      cv[Hn + h] = hp[(size_t)(b * Sn + Sn - 1) * Hn + h];
    }
    __syncthreads();
    if (tid < NLn * 16) {
      const int l = tid >> 4, c = tid & 15;
      float p = 0.f;
      #pragma unroll
      for (int k = c * 32; k < c * 32 + 32; ++k) p += cv[k] * Wi[k * NLn + l];
      ip[l][c] = p;
    }
    __syncthreads();
    if (tid < NLn) {
      float t = 0.f;
      #pragma unroll
      for (int c = 0; c < 16; ++c) t += ip[tid][c];
      outI[b * NLn + tid] = t;
    }
  }
}

// ---------------------------------------------------------------------------
extern "C" void kernel_launch(void* const* d_in, const int* in_sizes, int n_in,
                              void* d_out, int out_size, void* d_ws, size_t ws_size,
                              hipStream_t stream) {
  const float* hp     = (const float*)d_in[0];
  const float* c_slot = (const float*)d_in[1];
  const float* c_inte = (const float*)d_in[2];
  const float* W_SF   = (const float*)d_in[3];
  const float* V_SF   = (const float*)d_in[4];
  const float* V1     = (const float*)d_in[5];
  const float* V2w    = (const float*)d_in[6];
  const float* V2b    = (const float*)d_in[7];
  const float* wid    = (const float*)d_in[8];
  const float* Wi     = (const float*)d_in[9];
  const float* Ws     = (const float*)d_in[10];
  float* outS = (float*)d_out;                   // B*S*NS
  float* outI = (float*)d_out + Bn * Sn * NSn;   // B*NL

  float* ws = (float*)d_ws;
  float* ZT     = ws;                       // B*H*S (j-contig)
  float* g2     = ZT + (size_t)Bn * Sn * Hn;
  float* alphas = g2 + Bn * Hn;

  // hf + A(it=0) fused
  hipLaunchKernelGGL(k_hfA, dim3(256 + Bn), dim3(1024), 0, stream,
                     hp, V2w, V2b, c_slot, c_inte, W_SF, V_SF, ZT, g2);
  hipLaunchKernelGGL(k_C, dim3(Bn * Sn / 4), dim3(1024), 0, stream,
                     c_slot, V1, g2, ZT, wid, alphas);
  for (int it = 1; it < 3; ++it) {
    hipLaunchKernelGGL(k_A, dim3(Bn), dim3(1024), 0, stream,
                       c_slot, c_inte, W_SF, V_SF, alphas, g2);
    hipLaunchKernelGGL(k_C, dim3(Bn * Sn / 4), dim3(1024), 0, stream,
                       c_slot, V1, g2, ZT, wid, alphas);
  }
  hipLaunchKernelGGL(k_out, dim3(Bn * Sn / 8), dim3(512), 0, stream,
                     hp, c_slot, c_inte, g2, alphas, Wi, Ws, outS, outI);
}

// Round 15
// 104.560 us; speedup vs baseline: 1.2630x; 1.0884x over previous
//
#include <hip/hip_runtime.h>

#define Bn 16
#define Sn 128
#define Hn 256
#define NLn 22
#define NSn 122

#define K2c 2.8853900817779268f   // 2*log2(e)
#define L2Ec 1.4426950408889634f  // log2(e)

__device__ __forceinline__ float fexp2(float x) { return __builtin_amdgcn_exp2f(x); }
__device__ __forceinline__ float frcp(float x) { return __builtin_amdgcn_rcpf(x); }

union F4 { float4 v; float f[4]; };

// ---------------------------------------------------------------------------
// A-update body: rL -> m -> em -> f -> g2.  1024 threads = h(256) x kq(4).
// Writes g2[b][h] directly.  use_alpha=0 for iteration 0.
// ---------------------------------------------------------------------------
__device__ __forceinline__ void A_body(const float* __restrict__ c_slot,
                                       const float* __restrict__ c_inte,
                                       const float* __restrict__ W_SF,
                                       const float* __restrict__ V_SF,
                                       const float* __restrict__ alphas,
                                       float* __restrict__ g2,
                                       int b, int use_alpha,
                                       float* rL, float* fLq, float* aL,
                                       float (*pt)[Hn]) {
  const int tid = threadIdx.x;
  const int h = tid & (Hn - 1);
  const int kq = tid >> 8;

  if (use_alpha) {
    if (tid < Sn) aL[tid] = alphas[b * Sn + tid];
    __syncthreads();
    float ps = 0.f;
    #pragma unroll 8
    for (int s = kq * 32; s < kq * 32 + 32; ++s)
      ps += c_slot[(size_t)(b * Sn + s) * Hn + h] * aL[s];
    pt[kq][h] = ps;
    __syncthreads();
    if (!kq)
      rL[h] = c_inte[b * Hn + h] +
              g2[b * Hn + h] * (pt[0][h] + pt[1][h] + pt[2][h] + pt[3][h]);
  } else {
    if (!kq) rL[h] = c_inte[b * Hn + h];
  }
  __syncthreads();

  // m = rL @ W_SF (4-way k-split)
  float pm = 0.f;
  #pragma unroll 8
  for (int k = kq * 64; k < kq * 64 + 64; ++k)
    pm += rL[k] * W_SF[(size_t)k * Hn + h];
  __syncthreads();               // protect pt from rs-phase reads
  pt[kq][h] = pm;
  __syncthreads();
  const float m = pt[0][h] + pt[1][h] + pt[2][h] + pt[3][h];
  const float em = fexp2(fminf(fmaxf(K2c * m, -60.f), 60.f));

  // f partial: 32 s per kq
  float pr = 0.f;
  #pragma unroll 8
  for (int s = kq * 32; s < kq * 32 + 32; ++s) {
    float zc = fminf(fmaxf(K2c * c_slot[(size_t)(b * Sn + s) * Hn + h], -60.f), 60.f);
    pr += frcp(fmaf(fexp2(zc), em, 1.f));
  }
  __syncthreads();               // all m-reads of pt complete
  pt[kq][h] = pr;
  __syncthreads();
  if (!kq) fLq[h] = (float)Sn - 2.f * (pt[0][h] + pt[1][h] + pt[2][h] + pt[3][h]);
  __syncthreads();

  // g2 = fLq @ V_SF (4-way k-split)
  float pg = 0.f;
  #pragma unroll 8
  for (int k = kq * 64; k < kq * 64 + 64; ++k)
    pg += fLq[k] * V_SF[(size_t)k * Hn + h];
  __syncthreads();
  pt[kq][h] = pg;
  __syncthreads();
  if (!kq)
    g2[b * Hn + h] = pt[0][h] + pt[1][h] + pt[2][h] + pt[3][h];
}

// ---------------------------------------------------------------------------
// k_hfA: blocks 0..255: hf -> ZT4 (8 rows each).  ZT4 layout: [b][h/4][j][h%4]
// so k_C phase3 can read 4 h-values per lane with one dwordx4.
//        blocks 256..271: A-update for iteration 0 (no alphas) -> g2.
// ---------------------------------------------------------------------------
__global__ __launch_bounds__(1024) void k_hfA(const float* __restrict__ hp,
                                              const float* __restrict__ V2w,
                                              const float* __restrict__ V2b,
                                              const float* __restrict__ c_slot,
                                              const float* __restrict__ c_inte,
                                              const float* __restrict__ W_SF,
                                              const float* __restrict__ V_SF,
                                              float* __restrict__ ZT,
                                              float* __restrict__ g2) {
  __shared__ float xT[Hn][8];
  __shared__ float pp[3][Hn][8];
  __shared__ float rL[Hn];
  __shared__ float fLq[Hn];
  __shared__ float aL[Sn];
  __shared__ float pt[4][Hn];
  const int tid = threadIdx.x;
  const int blk = blockIdx.x;

  if (blk >= 256) {              // A-update, iteration 0
    A_body(c_slot, c_inte, W_SF, V_SF, nullptr, g2, blk - 256, 0,
           rL, fLq, aL, pt);
    return;
  }

  const int r0 = blk * 8;
  const int b = r0 >> 7;
  const int j0 = r0 & (Sn - 1);
  const int h = tid & (Hn - 1);
  const int kh = tid >> 8;       // 0..3
  xT[h][kh * 2]     = hp[(size_t)(r0 + kh * 2) * Hn + h];
  xT[h][kh * 2 + 1] = hp[(size_t)(r0 + kh * 2 + 1) * Hn + h];
  __syncthreads();
  float acc[8] = {0.f, 0.f, 0.f, 0.f, 0.f, 0.f, 0.f, 0.f};
  #pragma unroll 8
  for (int k = kh * 64; k < kh * 64 + 64; ++k) {
    const float v = V2w[(size_t)k * Hn + h];
    F4 xa, xb;
    xa.v = *(const float4*)&xT[k][0];
    xb.v = *(const float4*)&xT[k][4];
    acc[0] += xa.f[0] * v; acc[1] += xa.f[1] * v;
    acc[2] += xa.f[2] * v; acc[3] += xa.f[3] * v;
    acc[4] += xb.f[0] * v; acc[5] += xb.f[1] * v;
    acc[6] += xb.f[2] * v; acc[7] += xb.f[3] * v;
  }
  if (kh) {
    F4 s0, s1;
    s0.f[0] = acc[0]; s0.f[1] = acc[1]; s0.f[2] = acc[2]; s0.f[3] = acc[3];
    s1.f[0] = acc[4]; s1.f[1] = acc[5]; s1.f[2] = acc[6]; s1.f[3] = acc[7];
    *(float4*)&pp[kh - 1][h][0] = s0.v;
    *(float4*)&pp[kh - 1][h][4] = s1.v;
  }
  __syncthreads();
  if (!kh) {
    const float bj = V2b[h];
    // ZT4[b][h>>2][j][h&3]
    float* zb = ZT + (((size_t)b * (Hn / 4) + (h >> 2)) * Sn) * 4 + (h & 3);
    #pragma unroll
    for (int i = 0; i < 8; ++i) {
      float z = K2c * (acc[i] + pp[0][h][i] + pp[1][h][i] + pp[2][h][i] + bj);
      z = fminf(fmaxf(z, -60.f), 60.f);
      zb[(size_t)(j0 + i) * 4] = fexp2(z);
    }
  }
}

// ---------------------------------------------------------------------------
// k_A: iterations 1,2. 16 blocks (one per b) x 1024 threads. Writes g2.
// ---------------------------------------------------------------------------
__global__ __launch_bounds__(1024) void k_A(const float* __restrict__ c_slot,
                                            const float* __restrict__ c_inte,
                                            const float* __restrict__ W_SF,
                                            const float* __restrict__ V_SF,
                                            const float* __restrict__ alphas,
                                            float* __restrict__ g2) {
  __shared__ float rL[Hn];
  __shared__ float fLq[Hn];
  __shared__ float aL[Sn];
  __shared__ float pt[4][Hn];
  A_body(c_slot, c_inte, W_SF, V_SF, alphas, g2, blockIdx.x, 1,
         rL, fLq, aL, pt);
}

// ---------------------------------------------------------------------------
// k_C: scores. 512 blocks = (b, 4-row group), 1024 threads, ~25KB LDS.
// Phase3 reads ZT4 with dwordx4 (4 h-values per lane per load): 8 vector
// loads/thread instead of 32 scalar loads.
// ---------------------------------------------------------------------------
__global__ __launch_bounds__(1024) void k_C(const float* __restrict__ c_slot,
                                            const float* __restrict__ V1,
                                            const float* __restrict__ g2,
                                            const float* __restrict__ ZT,
                                            const float* __restrict__ wid,
                                            float* __restrict__ alphas) {
  __shared__ float bufA[Hn][4];    // xT
  __shared__ float bufB[Hn][4];    // YT
  __shared__ union {
    float pp[3][Hn][4];            // phase2 partials (12KB)
    float red[7][4][Sn];           // phase3 partials (14KB)
  } u;
  __shared__ float sc4[4][Sn];
  __shared__ float wL[Hn];

  const int tid = threadIdx.x;
  const int blk = blockIdx.x;
  const int b = blk >> 5;
  const int i0 = (blk & 31) * 4;
  const int h = tid & (Hn - 1);
  const int kq = tid >> 8;         // 0..3

  // phase1
  bufA[h][kq] = g2[b * Hn + h] * c_slot[(size_t)(b * Sn + i0 + kq) * Hn + h];
  if (tid < Hn) wL[tid] = wid[tid];
  __syncthreads();

  // phase2: sf = x @ V1 (4-way kq split) -> Y
  {
    float acc[4] = {0.f, 0.f, 0.f, 0.f};
    #pragma unroll 8
    for (int k = kq * 64; k < kq * 64 + 64; ++k) {
      const float v = V1[(size_t)k * Hn + h];
      F4 xa; xa.v = *(const float4*)&bufA[k][0];
      acc[0] += xa.f[0] * v; acc[1] += xa.f[1] * v;
      acc[2] += xa.f[2] * v; acc[3] += xa.f[3] * v;
    }
    if (kq) {
      F4 s0;
      s0.f[0] = acc[0]; s0.f[1] = acc[1]; s0.f[2] = acc[2]; s0.f[3] = acc[3];
      *(float4*)&u.pp[kq - 1][h][0] = s0.v;
    }
    __syncthreads();
    if (!kq) {
      #pragma unroll
      for (int i = 0; i < 4; ++i) {
        float z = K2c * (acc[i] + u.pp[0][h][i] + u.pp[1][h][i] + u.pp[2][h][i]);
        z = fminf(fmaxf(z, -60.f), 60.f);
        bufB[h][i] = fexp2(z);
      }
    }
  }
  __syncthreads();

  // phase3: ZT4 dwordx4 loads (lane = j), 8 loads x 4 h-values per thread
  const int j = tid & (Sn - 1);
  const int hq = tid >> 7;         // 0..7
  float a4[4] = {0.f, 0.f, 0.f, 0.f};
  // ZT4[b][hq*8 + t][j][e]
  const float* zp4 = ZT + (((size_t)b * (Hn / 4) + hq * 8) * Sn + j) * 4;
  #pragma unroll 2
  for (int t = 0; t < 8; ++t) {
    F4 z4; z4.v = *(const float4*)(zp4 + (size_t)t * Sn * 4);
    #pragma unroll
    for (int e = 0; e < 4; ++e) {
      const int hx = hq * 32 + t * 4 + e;
      const float wh = wL[hx];
      const float z = z4.f[e];
      F4 ya; ya.v = *(const float4*)&bufB[hx][0];
      a4[0] += wh * frcp(fmaf(ya.f[0], z, 1.f));
      a4[1] += wh * frcp(fmaf(ya.f[1], z, 1.f));
      a4[2] += wh * frcp(fmaf(ya.f[2], z, 1.f));
      a4[3] += wh * frcp(fmaf(ya.f[3], z, 1.f));
    }
  }
  if (hq) {
    #pragma unroll
    for (int i = 0; i < 4; ++i) u.red[hq - 1][i][j] = a4[i];
  }
  __syncthreads();
  if (!hq) {
    #pragma unroll
    for (int i = 0; i < 4; ++i) {
      float tot = a4[i];
      #pragma unroll
      for (int r = 0; r < 7; ++r) tot += u.red[r][i][j];
      sc4[i][j] = -2.f * L2Ec * tot;   // log2-domain score (const dropped)
    }
  }
  __syncthreads();

  // phase4: softmax, 4 rows x 32 lanes
  if (tid < 128) {
    const int row = tid >> 5;
    const int l5 = tid & 31;
    const float v0 = sc4[row][l5];
    const float v1 = sc4[row][l5 + 32];
    const float v2 = sc4[row][l5 + 64];
    const float v3 = sc4[row][l5 + 96];
    float mx = fmaxf(fmaxf(v0, v1), fmaxf(v2, v3));
    #pragma unroll
    for (int o = 16; o >= 1; o >>= 1) mx = fmaxf(mx, __shfl_xor(mx, o, 32));
    float sm = fexp2(v0 - mx) + fexp2(v1 - mx) + fexp2(v2 - mx) + fexp2(v3 - mx);
    #pragma unroll
    for (int o = 16; o >= 1; o >>= 1) sm += __shfl_xor(sm, o, 32);
    if (l5 == 0) {
      const int ig = i0 + row;
      alphas[b * Sn + ig] = fexp2(sc4[row][ig] - mx) * frcp(sm);
    }
  }
}

// ---------------------------------------------------------------------------
// k_out: 256 blocks x 512. All blocks: slot head (8 rows). Blocks 0..15 also
// do the intent head afterwards (disjoint LDS arrays).
// ---------------------------------------------------------------------------
__global__ __launch_bounds__(512) void k_out(const float* __restrict__ hp,
                                             const float* __restrict__ c_slot,
                                             const float* __restrict__ c_inte,
                                             const float* __restrict__ g2,
                                             const float* __restrict__ alphas,
                                             const float* __restrict__ Wi,
                                             const float* __restrict__ Ws,
                                             float* __restrict__ outS,
                                             float* __restrict__ outI) {
  __shared__ float bufA[Hn][8];
  __shared__ float bufB[Hn][8];
  __shared__ float red[3][8][Sn];
  __shared__ float aL[Sn];
  __shared__ float cv[2 * Hn];
  __shared__ float ptA[2][Hn];
  __shared__ float ip[NLn][16];
  const int tid = threadIdx.x;
  const int blk = blockIdx.x;
  const int r0 = blk * 8;
  const int b2 = r0 >> 7;

  if (tid < Hn) {
    #pragma unroll
    for (int i = 0; i < 8; ++i) bufA[tid][i] = hp[(size_t)(r0 + i) * Hn + tid];
  } else {
    const int t = tid - Hn;
    const float gv = g2[b2 * Hn + t];
    #pragma unroll
    for (int i = 0; i < 8; ++i)
      bufB[t][i] = gv * c_slot[(size_t)(r0 + i) * Hn + t];
  }
  __syncthreads();
  const int jc = tid & 127;
  const int kq = tid >> 7;
  float acc[8] = {0.f, 0.f, 0.f, 0.f, 0.f, 0.f, 0.f, 0.f};
  if (jc < NSn) {
    const float (*xb)[8] = (kq < 2) ? bufA : bufB;
    const int kg0 = kq * 128;
    const int koff = (kq < 2) ? kg0 : kg0 - 256;
    #pragma unroll 8
    for (int u = 0; u < 128; ++u) {
      const float v = Ws[(size_t)(kg0 + u) * NSn + jc];
      F4 xa, xb4;
      xa.v = *(const float4*)&xb[koff + u][0];
      xb4.v = *(const float4*)&xb[koff + u][4];
      acc[0] += xa.f[0] * v; acc[1] += xa.f[1] * v;
      acc[2] += xa.f[2] * v; acc[3] += xa.f[3] * v;
      acc[4] += xb4.f[0] * v; acc[5] += xb4.f[1] * v;
      acc[6] += xb4.f[2] * v; acc[7] += xb4.f[3] * v;
    }
  }
  if (kq) {
    #pragma unroll
    for (int i = 0; i < 8; ++i) red[kq - 1][i][jc] = acc[i];
  }
  __syncthreads();
  if (!kq && jc < NSn) {
    #pragma unroll
    for (int i = 0; i < 8; ++i)
      outS[(size_t)(r0 + i) * NSn + jc] =
          acc[i] + red[0][i][jc] + red[1][i][jc] + red[2][i][jc];
  }

  // intent head on blocks 0..15
  if (blk < Bn) {
    const int b = blk;
    if (tid < Sn) aL[tid] = alphas[b * Sn + tid];
    __syncthreads();
    const int h = tid & (Hn - 1);
    const int k2 = tid >> 8;
    float ps = 0.f;
    #pragma unroll 8
    for (int s = k2 * 64; s < k2 * 64 + 64; ++s)
      ps += c_slot[(size_t)(b * Sn + s) * Hn + h] * aL[s];
    ptA[k2][h] = ps;
    __syncthreads();
    if (!k2) {
      cv[h] = c_inte[b * Hn + h] + g2[b * Hn + h] * (ptA[0][h] + ptA[1][h]);
      cv[Hn + h] = hp[(size_t)(b * Sn + Sn - 1) * Hn + h];
    }
    __syncthreads();
    if (tid < NLn * 16) {
      const int l = tid >> 4, c = tid & 15;
      float p = 0.f;
      #pragma unroll
      for (int k = c * 32; k < c * 32 + 32; ++k) p += cv[k] * Wi[k * NLn + l];
      ip[l][c] = p;
    }
    __syncthreads();
    if (tid < NLn) {
      float t = 0.f;
      #pragma unroll
      for (int c = 0; c < 16; ++c) t += ip[tid][c];
      outI[b * NLn + tid] = t;
    }
  }
}

// ---------------------------------------------------------------------------
extern "C" void kernel_launch(void* const* d_in, const int* in_sizes, int n_in,
                              void* d_out, int out_size, void* d_ws, size_t ws_size,
                              hipStream_t stream) {
  const float* hp     = (const float*)d_in[0];
  const float* c_slot = (const float*)d_in[1];
  const float* c_inte = (const float*)d_in[2];
  const float* W_SF   = (const float*)d_in[3];
  const float* V_SF   = (const float*)d_in[4];
  const float* V1     = (const float*)d_in[5];
  const float* V2w    = (const float*)d_in[6];
  const float* V2b    = (const float*)d_in[7];
  const float* wid    = (const float*)d_in[8];
  const float* Wi     = (const float*)d_in[9];
  const float* Ws     = (const float*)d_in[10];
  float* outS = (float*)d_out;                   // B*S*NS
  float* outI = (float*)d_out + Bn * Sn * NSn;   // B*NL

  float* ws = (float*)d_ws;
  float* ZT     = ws;                       // B*(H/4)*S*4 (vectorized layout)
  float* g2     = ZT + (size_t)Bn * Sn * Hn;
  float* alphas = g2 + Bn * Hn;

  // hf + A(it=0) fused
  hipLaunchKernelGGL(k_hfA, dim3(256 + Bn), dim3(1024), 0, stream,
                     hp, V2w, V2b, c_slot, c_inte, W_SF, V_SF, ZT, g2);
  hipLaunchKernelGGL(k_C, dim3(Bn * Sn / 4), dim3(1024), 0, stream,
                     c_slot, V1, g2, ZT, wid, alphas);
  for (int it = 1; it < 3; ++it) {
    hipLaunchKernelGGL(k_A, dim3(Bn), dim3(1024), 0, stream,
                       c_slot, c_inte, W_SF, V_SF, alphas, g2);
    hipLaunchKernelGGL(k_C, dim3(Bn * Sn / 4), dim3(1024), 0, stream,
                       c_slot, V1, g2, ZT, wid, alphas);
  }
  hipLaunchKernelGGL(k_out, dim3(Bn * Sn / 8), dim3(512), 0, stream,
                     hp, c_slot, c_inte, g2, alphas, Wi, Ws, outS, outI);
}

// Round 16
// 102.926 us; speedup vs baseline: 1.2831x; 1.0159x over previous
//
#include <hip/hip_runtime.h>

#define Bn 16
#define Sn 128
#define Hn 256
#define NLn 22
#define NSn 122

#define K2c 2.8853900817779268f   // 2*log2(e)
#define L2Ec 1.4426950408889634f  // log2(e)

__device__ __forceinline__ float fexp2(float x) { return __builtin_amdgcn_exp2f(x); }
__device__ __forceinline__ float frcp(float x) { return __builtin_amdgcn_rcpf(x); }

union F4 { float4 v; float f[4]; };

// ---------------------------------------------------------------------------
// A-update body: rL -> m -> em -> f -> g2.  1024 threads = h(256) x kq(4).
// Writes g2[b][h] directly.  use_alpha=0 for iteration 0.
// ---------------------------------------------------------------------------
__device__ __forceinline__ void A_body(const float* __restrict__ c_slot,
                                       const float* __restrict__ c_inte,
                                       const float* __restrict__ W_SF,
                                       const float* __restrict__ V_SF,
                                       const float* __restrict__ alphas,
                                       float* __restrict__ g2,
                                       int b, int use_alpha,
                                       float* rL, float* fLq, float* aL,
                                       float (*pt)[Hn]) {
  const int tid = threadIdx.x;
  const int h = tid & (Hn - 1);
  const int kq = tid >> 8;

  if (use_alpha) {
    if (tid < Sn) aL[tid] = alphas[b * Sn + tid];
    __syncthreads();
    float ps = 0.f;
    #pragma unroll 8
    for (int s = kq * 32; s < kq * 32 + 32; ++s)
      ps += c_slot[(size_t)(b * Sn + s) * Hn + h] * aL[s];
    pt[kq][h] = ps;
    __syncthreads();
    if (!kq)
      rL[h] = c_inte[b * Hn + h] +
              g2[b * Hn + h] * (pt[0][h] + pt[1][h] + pt[2][h] + pt[3][h]);
  } else {
    if (!kq) rL[h] = c_inte[b * Hn + h];
  }
  __syncthreads();

  // m = rL @ W_SF (4-way k-split)
  float pm = 0.f;
  #pragma unroll 8
  for (int k = kq * 64; k < kq * 64 + 64; ++k)
    pm += rL[k] * W_SF[(size_t)k * Hn + h];
  __syncthreads();               // protect pt from rs-phase reads
  pt[kq][h] = pm;
  __syncthreads();
  const float m = pt[0][h] + pt[1][h] + pt[2][h] + pt[3][h];
  const float em = fexp2(fminf(fmaxf(K2c * m, -60.f), 60.f));

  // f partial: 32 s per kq
  float pr = 0.f;
  #pragma unroll 8
  for (int s = kq * 32; s < kq * 32 + 32; ++s) {
    float zc = fminf(fmaxf(K2c * c_slot[(size_t)(b * Sn + s) * Hn + h], -60.f), 60.f);
    pr += frcp(fmaf(fexp2(zc), em, 1.f));
  }
  __syncthreads();               // all m-reads of pt complete
  pt[kq][h] = pr;
  __syncthreads();
  if (!kq) fLq[h] = (float)Sn - 2.f * (pt[0][h] + pt[1][h] + pt[2][h] + pt[3][h]);
  __syncthreads();

  // g2 = fLq @ V_SF (4-way k-split)
  float pg = 0.f;
  #pragma unroll 8
  for (int k = kq * 64; k < kq * 64 + 64; ++k)
    pg += fLq[k] * V_SF[(size_t)k * Hn + h];
  __syncthreads();
  pt[kq][h] = pg;
  __syncthreads();
  if (!kq)
    g2[b * Hn + h] = pt[0][h] + pt[1][h] + pt[2][h] + pt[3][h];
}

// ---------------------------------------------------------------------------
// k_hfA: blocks 0..255: hf -> ZT (8 rows each, j-contiguous exp2(K2*hf)).
//        blocks 256..271: A-update for iteration 0 (no alphas) -> g2.
// ---------------------------------------------------------------------------
__global__ __launch_bounds__(1024) void k_hfA(const float* __restrict__ hp,
                                              const float* __restrict__ V2w,
                                              const float* __restrict__ V2b,
                                              const float* __restrict__ c_slot,
                                              const float* __restrict__ c_inte,
                                              const float* __restrict__ W_SF,
                                              const float* __restrict__ V_SF,
                                              float* __restrict__ ZT,
                                              float* __restrict__ g2) {
  __shared__ float xT[Hn][8];
  __shared__ float pp[3][Hn][8];
  __shared__ float rL[Hn];
  __shared__ float fLq[Hn];
  __shared__ float aL[Sn];
  __shared__ float pt[4][Hn];
  const int tid = threadIdx.x;
  const int blk = blockIdx.x;

  if (blk >= 256) {              // A-update, iteration 0
    A_body(c_slot, c_inte, W_SF, V_SF, nullptr, g2, blk - 256, 0,
           rL, fLq, aL, pt);
    return;
  }

  const int r0 = blk * 8;
  const int b = r0 >> 7;
  const int j0 = r0 & (Sn - 1);
  const int h = tid & (Hn - 1);
  const int kh = tid >> 8;       // 0..3
  xT[h][kh * 2]     = hp[(size_t)(r0 + kh * 2) * Hn + h];
  xT[h][kh * 2 + 1] = hp[(size_t)(r0 + kh * 2 + 1) * Hn + h];
  __syncthreads();
  float acc[8] = {0.f, 0.f, 0.f, 0.f, 0.f, 0.f, 0.f, 0.f};
  #pragma unroll 8
  for (int k = kh * 64; k < kh * 64 + 64; ++k) {
    const float v = V2w[(size_t)k * Hn + h];
    F4 xa, xb;
    xa.v = *(const float4*)&xT[k][0];
    xb.v = *(const float4*)&xT[k][4];
    acc[0] += xa.f[0] * v; acc[1] += xa.f[1] * v;
    acc[2] += xa.f[2] * v; acc[3] += xa.f[3] * v;
    acc[4] += xb.f[0] * v; acc[5] += xb.f[1] * v;
    acc[6] += xb.f[2] * v; acc[7] += xb.f[3] * v;
  }
  if (kh) {
    F4 s0, s1;
    s0.f[0] = acc[0]; s0.f[1] = acc[1]; s0.f[2] = acc[2]; s0.f[3] = acc[3];
    s1.f[0] = acc[4]; s1.f[1] = acc[5]; s1.f[2] = acc[6]; s1.f[3] = acc[7];
    *(float4*)&pp[kh - 1][h][0] = s0.v;
    *(float4*)&pp[kh - 1][h][4] = s1.v;
  }
  __syncthreads();
  if (!kh) {
    const float bj = V2b[h];
    F4 o0, o1;
    #pragma unroll
    for (int i = 0; i < 8; ++i) {
      float z = K2c * (acc[i] + pp[0][h][i] + pp[1][h][i] + pp[2][h][i] + bj);
      z = fminf(fmaxf(z, -60.f), 60.f);
      if (i < 4) o0.f[i] = fexp2(z); else o1.f[i - 4] = fexp2(z);
    }
    *(float4*)&ZT[((size_t)b * Hn + h) * Sn + j0] = o0.v;
    *(float4*)&ZT[((size_t)b * Hn + h) * Sn + j0 + 4] = o1.v;
  }
}

// ---------------------------------------------------------------------------
// k_A: iterations 1,2. 16 blocks (one per b) x 1024 threads. Writes g2.
// ---------------------------------------------------------------------------
__global__ __launch_bounds__(1024) void k_A(const float* __restrict__ c_slot,
                                            const float* __restrict__ c_inte,
                                            const float* __restrict__ W_SF,
                                            const float* __restrict__ V_SF,
                                            const float* __restrict__ alphas,
                                            float* __restrict__ g2) {
  __shared__ float rL[Hn];
  __shared__ float fLq[Hn];
  __shared__ float aL[Sn];
  __shared__ float pt[4][Hn];
  A_body(c_slot, c_inte, W_SF, V_SF, alphas, g2, blockIdx.x, 1,
         rL, fLq, aL, pt);
}

// ---------------------------------------------------------------------------
// k_C: scores. 256 blocks = (b, 8-row group), 1024 threads, ~49KB LDS ->
// 2 blocks/CU, 32 waves. Halves V1 + ZT L2 traffic vs the 4-row variant
// (each block amortizes the full-V1 read over 8 output rows instead of 4).
//   phase1: stage x = g2*c_slot (2 rows/thread); wid -> LDS
//   phase2: sf = x @ V1 (4-way kq split, acc[8]) -> Y in LDS
//   phase3: acc_ij = sum_h wid[h]*rcp(1+Y_i[h]*ZT[h][j])  (8-way hq split)
//   phase4: 7-way reduce; row softmax over j; emit diag alphas.
// ---------------------------------------------------------------------------
__global__ __launch_bounds__(1024) void k_C(const float* __restrict__ c_slot,
                                            const float* __restrict__ V1,
                                            const float* __restrict__ g2,
                                            const float* __restrict__ ZT,
                                            const float* __restrict__ wid,
                                            float* __restrict__ alphas) {
  __shared__ float bufA[Hn][8];    // xT
  __shared__ float bufB[Hn][8];    // YT
  __shared__ union {
    float pp[3][Hn][8];            // phase2 partials (24KB)
    float red[7][8][Sn];           // phase3 partials (28KB)
  } u;
  __shared__ float sc8[8][Sn];
  __shared__ float wL[Hn];

  const int tid = threadIdx.x;
  const int blk = blockIdx.x;
  const int b = blk >> 4;
  const int i0 = (blk & 15) * 8;
  const int h = tid & (Hn - 1);
  const int kq = tid >> 8;         // 0..3

  // phase1: 2 rows per thread
  {
    const float gv = g2[b * Hn + h];
    const int ii = kq * 2;
    bufA[h][ii]     = gv * c_slot[(size_t)(b * Sn + i0 + ii) * Hn + h];
    bufA[h][ii + 1] = gv * c_slot[(size_t)(b * Sn + i0 + ii + 1) * Hn + h];
    if (tid < Hn) wL[tid] = wid[tid];
  }
  __syncthreads();

  // phase2: sf = x @ V1 (4-way kq split) -> Y
  {
    float acc[8] = {0.f, 0.f, 0.f, 0.f, 0.f, 0.f, 0.f, 0.f};
    #pragma unroll 8
    for (int k = kq * 64; k < kq * 64 + 64; ++k) {
      const float v = V1[(size_t)k * Hn + h];
      F4 xa, xb;
      xa.v = *(const float4*)&bufA[k][0];
      xb.v = *(const float4*)&bufA[k][4];
      acc[0] += xa.f[0] * v; acc[1] += xa.f[1] * v;
      acc[2] += xa.f[2] * v; acc[3] += xa.f[3] * v;
      acc[4] += xb.f[0] * v; acc[5] += xb.f[1] * v;
      acc[6] += xb.f[2] * v; acc[7] += xb.f[3] * v;
    }
    if (kq) {
      F4 s0, s1;
      s0.f[0] = acc[0]; s0.f[1] = acc[1]; s0.f[2] = acc[2]; s0.f[3] = acc[3];
      s1.f[0] = acc[4]; s1.f[1] = acc[5]; s1.f[2] = acc[6]; s1.f[3] = acc[7];
      *(float4*)&u.pp[kq - 1][h][0] = s0.v;
      *(float4*)&u.pp[kq - 1][h][4] = s1.v;
    }
    __syncthreads();
    if (!kq) {
      #pragma unroll
      for (int i = 0; i < 8; ++i) {
        float z = K2c * (acc[i] + u.pp[0][h][i] + u.pp[1][h][i] + u.pp[2][h][i]);
        z = fminf(fmaxf(z, -60.f), 60.f);
        bufB[h][i] = fexp2(z);
      }
    }
  }
  __syncthreads();

  // phase3: inline coalesced ZT loads (lane = j), 32 hh per thread
  const int j = tid & (Sn - 1);
  const int hq = tid >> 7;         // 0..7
  float a8[8] = {0.f, 0.f, 0.f, 0.f, 0.f, 0.f, 0.f, 0.f};
  const float* zp = ZT + ((size_t)b * Hn + hq * 32) * Sn + j;
  #pragma unroll 4
  for (int hh = 0; hh < 32; ++hh) {
    const float z = zp[(size_t)hh * Sn];
    const float wh = wL[hq * 32 + hh];
    F4 ya, yb;
    ya.v = *(const float4*)&bufB[hq * 32 + hh][0];
    yb.v = *(const float4*)&bufB[hq * 32 + hh][4];
    a8[0] += wh * frcp(fmaf(ya.f[0], z, 1.f));
    a8[1] += wh * frcp(fmaf(ya.f[1], z, 1.f));
    a8[2] += wh * frcp(fmaf(ya.f[2], z, 1.f));
    a8[3] += wh * frcp(fmaf(ya.f[3], z, 1.f));
    a8[4] += wh * frcp(fmaf(yb.f[0], z, 1.f));
    a8[5] += wh * frcp(fmaf(yb.f[1], z, 1.f));
    a8[6] += wh * frcp(fmaf(yb.f[2], z, 1.f));
    a8[7] += wh * frcp(fmaf(yb.f[3], z, 1.f));
  }
  if (hq) {
    #pragma unroll
    for (int i = 0; i < 8; ++i) u.red[hq - 1][i][j] = a8[i];
  }
  __syncthreads();
  if (!hq) {
    #pragma unroll
    for (int i = 0; i < 8; ++i) {
      float tot = a8[i];
      #pragma unroll
      for (int r = 0; r < 7; ++r) tot += u.red[r][i][j];
      sc8[i][j] = -2.f * L2Ec * tot;   // log2-domain score (const dropped)
    }
  }
  __syncthreads();

  // phase4: softmax, 8 rows x 32 lanes
  if (tid < 256) {
    const int row = tid >> 5;
    const int l5 = tid & 31;
    const float v0 = sc8[row][l5];
    const float v1 = sc8[row][l5 + 32];
    const float v2 = sc8[row][l5 + 64];
    const float v3 = sc8[row][l5 + 96];
    float mx = fmaxf(fmaxf(v0, v1), fmaxf(v2, v3));
    #pragma unroll
    for (int o = 16; o >= 1; o >>= 1) mx = fmaxf(mx, __shfl_xor(mx, o, 32));
    float sm = fexp2(v0 - mx) + fexp2(v1 - mx) + fexp2(v2 - mx) + fexp2(v3 - mx);
    #pragma unroll
    for (int o = 16; o >= 1; o >>= 1) sm += __shfl_xor(sm, o, 32);
    if (l5 == 0) {
      const int ig = i0 + row;
      alphas[b * Sn + ig] = fexp2(sc8[row][ig] - mx) * frcp(sm);
    }
  }
}

// ---------------------------------------------------------------------------
// k_out: 256 blocks x 512. All blocks: slot head (8 rows). Blocks 0..15 also
// do the intent head afterwards (disjoint LDS arrays).
// ---------------------------------------------------------------------------
__global__ __launch_bounds__(512) void k_out(const float* __restrict__ hp,
                                             const float* __restrict__ c_slot,
                                             const float* __restrict__ c_inte,
                                             const float* __restrict__ g2,
                                             const float* __restrict__ alphas,
                                             const float* __restrict__ Wi,
                                             const float* __restrict__ Ws,
                                             float* __restrict__ outS,
                                             float* __restrict__ outI) {
  __shared__ float bufA[Hn][8];
  __shared__ float bufB[Hn][8];
  __shared__ float red[3][8][Sn];
  __shared__ float aL[Sn];
  __shared__ float cv[2 * Hn];
  __shared__ float ptA[2][Hn];
  __shared__ float ip[NLn][16];
  const int tid = threadIdx.x;
  const int blk = blockIdx.x;
  const int r0 = blk * 8;
  const int b2 = r0 >> 7;

  if (tid < Hn) {
    #pragma unroll
    for (int i = 0; i < 8; ++i) bufA[tid][i] = hp[(size_t)(r0 + i) * Hn + tid];
  } else {
    const int t = tid - Hn;
    const float gv = g2[b2 * Hn + t];
    #pragma unroll
    for (int i = 0; i < 8; ++i)
      bufB[t][i] = gv * c_slot[(size_t)(r0 + i) * Hn + t];
  }
  __syncthreads();
  const int jc = tid & 127;
  const int kq = tid >> 7;
  float acc[8] = {0.f, 0.f, 0.f, 0.f, 0.f, 0.f, 0.f, 0.f};
  if (jc < NSn) {
    const float (*xb)[8] = (kq < 2) ? bufA : bufB;
    const int kg0 = kq * 128;
    const int koff = (kq < 2) ? kg0 : kg0 - 256;
    #pragma unroll 8
    for (int u = 0; u < 128; ++u) {
      const float v = Ws[(size_t)(kg0 + u) * NSn + jc];
      F4 xa, xb4;
      xa.v = *(const float4*)&xb[koff + u][0];
      xb4.v = *(const float4*)&xb[koff + u][4];
      acc[0] += xa.f[0] * v; acc[1] += xa.f[1] * v;
      acc[2] += xa.f[2] * v; acc[3] += xa.f[3] * v;
      acc[4] += xb4.f[0] * v; acc[5] += xb4.f[1] * v;
      acc[6] += xb4.f[2] * v; acc[7] += xb4.f[3] * v;
    }
  }
  if (kq) {
    #pragma unroll
    for (int i = 0; i < 8; ++i) red[kq - 1][i][jc] = acc[i];
  }
  __syncthreads();
  if (!kq && jc < NSn) {
    #pragma unroll
    for (int i = 0; i < 8; ++i)
      outS[(size_t)(r0 + i) * NSn + jc] =
          acc[i] + red[0][i][jc] + red[1][i][jc] + red[2][i][jc];
  }

  // intent head on blocks 0..15
  if (blk < Bn) {
    const int b = blk;
    if (tid < Sn) aL[tid] = alphas[b * Sn + tid];
    __syncthreads();
    const int h = tid & (Hn - 1);
    const int k2 = tid >> 8;
    float ps = 0.f;
    #pragma unroll 8
    for (int s = k2 * 64; s < k2 * 64 + 64; ++s)
      ps += c_slot[(size_t)(b * Sn + s) * Hn + h] * aL[s];
    ptA[k2][h] = ps;
    __syncthreads();
    if (!k2) {
      cv[h] = c_inte[b * Hn + h] + g2[b * Hn + h] * (ptA[0][h] + ptA[1][h]);
      cv[Hn + h] = hp[(size_t)(b * Sn + Sn - 1) * Hn + h];
    }
    __syncthreads();
    if (tid < NLn * 16) {
      const int l = tid >> 4, c = tid & 15;
      float p = 0.f;
      #pragma unroll
      for (int k = c * 32; k < c * 32 + 32; ++k) p += cv[k] * Wi[k * NLn + l];
      ip[l][c] = p;
    }
    __syncthreads();
    if (tid < NLn) {
      float t = 0.f;
      #pragma unroll
      for (int c = 0; c < 16; ++c) t += ip[tid][c];
      outI[b * NLn + tid] = t;
    }
  }
}

// ---------------------------------------------------------------------------
extern "C" void kernel_launch(void* const* d_in, const int* in_sizes, int n_in,
                              void* d_out, int out_size, void* d_ws, size_t ws_size,
                              hipStream_t stream) {
  const float* hp     = (const float*)d_in[0];
  const float* c_slot = (const float*)d_in[1];
  const float* c_inte = (const float*)d_in[2];
  const float* W_SF   = (const float*)d_in[3];
  const float* V_SF   = (const float*)d_in[4];
  const float* V1     = (const float*)d_in[5];
  const float* V2w    = (const float*)d_in[6];
  const float* V2b    = (const float*)d_in[7];
  const float* wid    = (const float*)d_in[8];
  const float* Wi     = (const float*)d_in[9];
  const float* Ws     = (const float*)d_in[10];
  float* outS = (float*)d_out;                   // B*S*NS
  float* outI = (float*)d_out + Bn * Sn * NSn;   // B*NL

  float* ws = (float*)d_ws;
  float* ZT     = ws;                       // B*H*S (j-contig)
  float* g2     = ZT + (size_t)Bn * Sn * Hn;
  float* alphas = g2 + Bn * Hn;

  // hf + A(it=0) fused
  hipLaunchKernelGGL(k_hfA, dim3(256 + Bn), dim3(1024), 0, stream,
                     hp, V2w, V2b, c_slot, c_inte, W_SF, V_SF, ZT, g2);
  hipLaunchKernelGGL(k_C, dim3(Bn * Sn / 8), dim3(1024), 0, stream,
                     c_slot, V1, g2, ZT, wid, alphas);
  for (int it = 1; it < 3; ++it) {
    hipLaunchKernelGGL(k_A, dim3(Bn), dim3(1024), 0, stream,
                       c_slot, c_inte, W_SF, V_SF, alphas, g2);
    hipLaunchKernelGGL(k_C, dim3(Bn * Sn / 8), dim3(1024), 0, stream,
                       c_slot, V1, g2, ZT, wid, alphas);
  }
  hipLaunchKernelGGL(k_out, dim3(Bn * Sn / 8), dim3(512), 0, stream,
                     hp, c_slot, c_inte, g2, alphas, Wi, Ws, outS, outI);
}

// Round 17
// 96.766 us; speedup vs baseline: 1.3647x; 1.0637x over previous
//
#include <hip/hip_runtime.h>

#define Bn 16
#define Sn 128
#define Hn 256
#define NLn 22
#define NSn 122

#define K2c 2.8853900817779268f   // 2*log2(e)
#define L2Ec 1.4426950408889634f  // log2(e)

__device__ __forceinline__ float fexp2(float x) { return __builtin_amdgcn_exp2f(x); }
__device__ __forceinline__ float frcp(float x) { return __builtin_amdgcn_rcpf(x); }

union F4 { float4 v; float f[4]; };

// ---------------------------------------------------------------------------
// A-update body: rL -> m -> em -> f -> g2.  1024 threads = h(256) x kq(4).
// Writes g2[b][h] directly.  use_alpha=0 for iteration 0.
// ---------------------------------------------------------------------------
__device__ __forceinline__ void A_body(const float* __restrict__ c_slot,
                                       const float* __restrict__ c_inte,
                                       const float* __restrict__ W_SF,
                                       const float* __restrict__ V_SF,
                                       const float* __restrict__ alphas,
                                       float* __restrict__ g2,
                                       int b, int use_alpha,
                                       float* rL, float* fLq, float* aL,
                                       float (*pt)[Hn]) {
  const int tid = threadIdx.x;
  const int h = tid & (Hn - 1);
  const int kq = tid >> 8;

  if (use_alpha) {
    if (tid < Sn) aL[tid] = alphas[b * Sn + tid];
    __syncthreads();
    float ps = 0.f;
    #pragma unroll 8
    for (int s = kq * 32; s < kq * 32 + 32; ++s)
      ps += c_slot[(size_t)(b * Sn + s) * Hn + h] * aL[s];
    pt[kq][h] = ps;
    __syncthreads();
    if (!kq)
      rL[h] = c_inte[b * Hn + h] +
              g2[b * Hn + h] * (pt[0][h] + pt[1][h] + pt[2][h] + pt[3][h]);
  } else {
    if (!kq) rL[h] = c_inte[b * Hn + h];
  }
  __syncthreads();

  // m = rL @ W_SF (4-way k-split)
  float pm = 0.f;
  #pragma unroll 8
  for (int k = kq * 64; k < kq * 64 + 64; ++k)
    pm += rL[k] * W_SF[(size_t)k * Hn + h];
  __syncthreads();               // protect pt from rs-phase reads
  pt[kq][h] = pm;
  __syncthreads();
  const float m = pt[0][h] + pt[1][h] + pt[2][h] + pt[3][h];
  const float em = fexp2(fminf(fmaxf(K2c * m, -60.f), 60.f));

  // f partial: 32 s per kq
  float pr = 0.f;
  #pragma unroll 8
  for (int s = kq * 32; s < kq * 32 + 32; ++s) {
    float zc = fminf(fmaxf(K2c * c_slot[(size_t)(b * Sn + s) * Hn + h], -60.f), 60.f);
    pr += frcp(fmaf(fexp2(zc), em, 1.f));
  }
  __syncthreads();               // all m-reads of pt complete
  pt[kq][h] = pr;
  __syncthreads();
  if (!kq) fLq[h] = (float)Sn - 2.f * (pt[0][h] + pt[1][h] + pt[2][h] + pt[3][h]);
  __syncthreads();

  // g2 = fLq @ V_SF (4-way k-split)
  float pg = 0.f;
  #pragma unroll 8
  for (int k = kq * 64; k < kq * 64 + 64; ++k)
    pg += fLq[k] * V_SF[(size_t)k * Hn + h];
  __syncthreads();
  pt[kq][h] = pg;
  __syncthreads();
  if (!kq)
    g2[b * Hn + h] = pt[0][h] + pt[1][h] + pt[2][h] + pt[3][h];
}

// ---------------------------------------------------------------------------
// k_hfA: blocks 0..255: hf -> ZT (8 rows each, j-contiguous exp2(K2*hf)).
//        blocks 256..271: A-update for iteration 0 (no alphas) -> g2.
// ---------------------------------------------------------------------------
__global__ __launch_bounds__(1024) void k_hfA(const float* __restrict__ hp,
                                              const float* __restrict__ V2w,
                                              const float* __restrict__ V2b,
                                              const float* __restrict__ c_slot,
                                              const float* __restrict__ c_inte,
                                              const float* __restrict__ W_SF,
                                              const float* __restrict__ V_SF,
                                              float* __restrict__ ZT,
                                              float* __restrict__ g2) {
  __shared__ float xT[Hn][8];
  __shared__ float pp[3][Hn][8];
  __shared__ float rL[Hn];
  __shared__ float fLq[Hn];
  __shared__ float aL[Sn];
  __shared__ float pt[4][Hn];
  const int tid = threadIdx.x;
  const int blk = blockIdx.x;

  if (blk >= 256) {              // A-update, iteration 0
    A_body(c_slot, c_inte, W_SF, V_SF, nullptr, g2, blk - 256, 0,
           rL, fLq, aL, pt);
    return;
  }

  const int r0 = blk * 8;
  const int b = r0 >> 7;
  const int j0 = r0 & (Sn - 1);
  const int h = tid & (Hn - 1);
  const int kh = tid >> 8;       // 0..3
  xT[h][kh * 2]     = hp[(size_t)(r0 + kh * 2) * Hn + h];
  xT[h][kh * 2 + 1] = hp[(size_t)(r0 + kh * 2 + 1) * Hn + h];
  __syncthreads();
  float acc[8] = {0.f, 0.f, 0.f, 0.f, 0.f, 0.f, 0.f, 0.f};
  #pragma unroll 8
  for (int k = kh * 64; k < kh * 64 + 64; ++k) {
    const float v = V2w[(size_t)k * Hn + h];
    F4 xa, xb;
    xa.v = *(const float4*)&xT[k][0];
    xb.v = *(const float4*)&xT[k][4];
    acc[0] += xa.f[0] * v; acc[1] += xa.f[1] * v;
    acc[2] += xa.f[2] * v; acc[3] += xa.f[3] * v;
    acc[4] += xb.f[0] * v; acc[5] += xb.f[1] * v;
    acc[6] += xb.f[2] * v; acc[7] += xb.f[3] * v;
  }
  if (kh) {
    F4 s0, s1;
    s0.f[0] = acc[0]; s0.f[1] = acc[1]; s0.f[2] = acc[2]; s0.f[3] = acc[3];
    s1.f[0] = acc[4]; s1.f[1] = acc[5]; s1.f[2] = acc[6]; s1.f[3] = acc[7];
    *(float4*)&pp[kh - 1][h][0] = s0.v;
    *(float4*)&pp[kh - 1][h][4] = s1.v;
  }
  __syncthreads();
  if (!kh) {
    const float bj = V2b[h];
    F4 o0, o1;
    #pragma unroll
    for (int i = 0; i < 8; ++i) {
      float z = K2c * (acc[i] + pp[0][h][i] + pp[1][h][i] + pp[2][h][i] + bj);
      z = fminf(fmaxf(z, -60.f), 60.f);
      if (i < 4) o0.f[i] = fexp2(z); else o1.f[i - 4] = fexp2(z);
    }
    *(float4*)&ZT[((size_t)b * Hn + h) * Sn + j0] = o0.v;
    *(float4*)&ZT[((size_t)b * Hn + h) * Sn + j0 + 4] = o1.v;
  }
}

// ---------------------------------------------------------------------------
// k_A: iterations 1,2. 16 blocks (one per b) x 1024 threads. Writes g2.
// ---------------------------------------------------------------------------
__global__ __launch_bounds__(1024) void k_A(const float* __restrict__ c_slot,
                                            const float* __restrict__ c_inte,
                                            const float* __restrict__ W_SF,
                                            const float* __restrict__ V_SF,
                                            const float* __restrict__ alphas,
                                            float* __restrict__ g2) {
  __shared__ float rL[Hn];
  __shared__ float fLq[Hn];
  __shared__ float aL[Sn];
  __shared__ float pt[4][Hn];
  A_body(c_slot, c_inte, W_SF, V_SF, alphas, g2, blockIdx.x, 1,
         rL, fLq, aL, pt);
}

// ---------------------------------------------------------------------------
// k_C: scores. 256 blocks = (b, 8-row group), 1024 threads, ~49KB LDS.
// XCD-aware mapping (T1): b = blk & 15 so blk%8 == b%8 — all 16 row-group
// blocks of a given b dispatch to the same XCD, making the 16x re-read of
// that b's ZT/c_slot slices local-L2 hits instead of L3 round-trips.
//   phase1: stage x = g2*c_slot (2 rows/thread); wid -> LDS
//   phase2: sf = x @ V1 (4-way kq split, acc[8]) -> Y in LDS
//   phase3: acc_ij = sum_h wid[h]*rcp(1+Y_i[h]*ZT[h][j])  (8-way hq split)
//   phase4: 7-way reduce; row softmax over j; emit diag alphas.
// ---------------------------------------------------------------------------
__global__ __launch_bounds__(1024) void k_C(const float* __restrict__ c_slot,
                                            const float* __restrict__ V1,
                                            const float* __restrict__ g2,
                                            const float* __restrict__ ZT,
                                            const float* __restrict__ wid,
                                            float* __restrict__ alphas) {
  __shared__ float bufA[Hn][8];    // xT
  __shared__ float bufB[Hn][8];    // YT
  __shared__ union {
    float pp[3][Hn][8];            // phase2 partials (24KB)
    float red[7][8][Sn];           // phase3 partials (28KB)
  } u;
  __shared__ float sc8[8][Sn];
  __shared__ float wL[Hn];

  const int tid = threadIdx.x;
  const int blk = blockIdx.x;
  const int b = blk & 15;          // T1: same-b blocks -> same XCD
  const int i0 = (blk >> 4) * 8;
  const int h = tid & (Hn - 1);
  const int kq = tid >> 8;         // 0..3

  // phase1: 2 rows per thread
  {
    const float gv = g2[b * Hn + h];
    const int ii = kq * 2;
    bufA[h][ii]     = gv * c_slot[(size_t)(b * Sn + i0 + ii) * Hn + h];
    bufA[h][ii + 1] = gv * c_slot[(size_t)(b * Sn + i0 + ii + 1) * Hn + h];
    if (tid < Hn) wL[tid] = wid[tid];
  }
  __syncthreads();

  // phase2: sf = x @ V1 (4-way kq split) -> Y
  {
    float acc[8] = {0.f, 0.f, 0.f, 0.f, 0.f, 0.f, 0.f, 0.f};
    #pragma unroll 8
    for (int k = kq * 64; k < kq * 64 + 64; ++k) {
      const float v = V1[(size_t)k * Hn + h];
      F4 xa, xb;
      xa.v = *(const float4*)&bufA[k][0];
      xb.v = *(const float4*)&bufA[k][4];
      acc[0] += xa.f[0] * v; acc[1] += xa.f[1] * v;
      acc[2] += xa.f[2] * v; acc[3] += xa.f[3] * v;
      acc[4] += xb.f[0] * v; acc[5] += xb.f[1] * v;
      acc[6] += xb.f[2] * v; acc[7] += xb.f[3] * v;
    }
    if (kq) {
      F4 s0, s1;
      s0.f[0] = acc[0]; s0.f[1] = acc[1]; s0.f[2] = acc[2]; s0.f[3] = acc[3];
      s1.f[0] = acc[4]; s1.f[1] = acc[5]; s1.f[2] = acc[6]; s1.f[3] = acc[7];
      *(float4*)&u.pp[kq - 1][h][0] = s0.v;
      *(float4*)&u.pp[kq - 1][h][4] = s1.v;
    }
    __syncthreads();
    if (!kq) {
      #pragma unroll
      for (int i = 0; i < 8; ++i) {
        float z = K2c * (acc[i] + u.pp[0][h][i] + u.pp[1][h][i] + u.pp[2][h][i]);
        z = fminf(fmaxf(z, -60.f), 60.f);
        bufB[h][i] = fexp2(z);
      }
    }
  }
  __syncthreads();

  // phase3: inline coalesced ZT loads (lane = j), 32 hh per thread
  const int j = tid & (Sn - 1);
  const int hq = tid >> 7;         // 0..7
  float a8[8] = {0.f, 0.f, 0.f, 0.f, 0.f, 0.f, 0.f, 0.f};
  const float* zp = ZT + ((size_t)b * Hn + hq * 32) * Sn + j;
  #pragma unroll 4
  for (int hh = 0; hh < 32; ++hh) {
    const float z = zp[(size_t)hh * Sn];
    const float wh = wL[hq * 32 + hh];
    F4 ya, yb;
    ya.v = *(const float4*)&bufB[hq * 32 + hh][0];
    yb.v = *(const float4*)&bufB[hq * 32 + hh][4];
    a8[0] += wh * frcp(fmaf(ya.f[0], z, 1.f));
    a8[1] += wh * frcp(fmaf(ya.f[1], z, 1.f));
    a8[2] += wh * frcp(fmaf(ya.f[2], z, 1.f));
    a8[3] += wh * frcp(fmaf(ya.f[3], z, 1.f));
    a8[4] += wh * frcp(fmaf(yb.f[0], z, 1.f));
    a8[5] += wh * frcp(fmaf(yb.f[1], z, 1.f));
    a8[6] += wh * frcp(fmaf(yb.f[2], z, 1.f));
    a8[7] += wh * frcp(fmaf(yb.f[3], z, 1.f));
  }
  if (hq) {
    #pragma unroll
    for (int i = 0; i < 8; ++i) u.red[hq - 1][i][j] = a8[i];
  }
  __syncthreads();
  if (!hq) {
    #pragma unroll
    for (int i = 0; i < 8; ++i) {
      float tot = a8[i];
      #pragma unroll
      for (int r = 0; r < 7; ++r) tot += u.red[r][i][j];
      sc8[i][j] = -2.f * L2Ec * tot;   // log2-domain score (const dropped)
    }
  }
  __syncthreads();

  // phase4: softmax, 8 rows x 32 lanes
  if (tid < 256) {
    const int row = tid >> 5;
    const int l5 = tid & 31;
    const float v0 = sc8[row][l5];
    const float v1 = sc8[row][l5 + 32];
    const float v2 = sc8[row][l5 + 64];
    const float v3 = sc8[row][l5 + 96];
    float mx = fmaxf(fmaxf(v0, v1), fmaxf(v2, v3));
    #pragma unroll
    for (int o = 16; o >= 1; o >>= 1) mx = fmaxf(mx, __shfl_xor(mx, o, 32));
    float sm = fexp2(v0 - mx) + fexp2(v1 - mx) + fexp2(v2 - mx) + fexp2(v3 - mx);
    #pragma unroll
    for (int o = 16; o >= 1; o >>= 1) sm += __shfl_xor(sm, o, 32);
    if (l5 == 0) {
      const int ig = i0 + row;
      alphas[b * Sn + ig] = fexp2(sc8[row][ig] - mx) * frcp(sm);
    }
  }
}

// ---------------------------------------------------------------------------
// k_out: 256 blocks x 512. All blocks: slot head (8 rows). Blocks 0..15 also
// do the intent head afterwards (disjoint LDS arrays).
// ---------------------------------------------------------------------------
__global__ __launch_bounds__(512) void k_out(const float* __restrict__ hp,
                                             const float* __restrict__ c_slot,
                                             const float* __restrict__ c_inte,
                                             const float* __restrict__ g2,
                                             const float* __restrict__ alphas,
                                             const float* __restrict__ Wi,
                                             const float* __restrict__ Ws,
                                             float* __restrict__ outS,
                                             float* __restrict__ outI) {
  __shared__ float bufA[Hn][8];
  __shared__ float bufB[Hn][8];
  __shared__ float red[3][8][Sn];
  __shared__ float aL[Sn];
  __shared__ float cv[2 * Hn];
  __shared__ float ptA[2][Hn];
  __shared__ float ip[NLn][16];
  const int tid = threadIdx.x;
  const int blk = blockIdx.x;
  const int r0 = blk * 8;
  const int b2 = r0 >> 7;

  if (tid < Hn) {
    #pragma unroll
    for (int i = 0; i < 8; ++i) bufA[tid][i] = hp[(size_t)(r0 + i) * Hn + tid];
  } else {
    const int t = tid - Hn;
    const float gv = g2[b2 * Hn + t];
    #pragma unroll
    for (int i = 0; i < 8; ++i)
      bufB[t][i] = gv * c_slot[(size_t)(r0 + i) * Hn + t];
  }
  __syncthreads();
  const int jc = tid & 127;
  const int kq = tid >> 7;
  float acc[8] = {0.f, 0.f, 0.f, 0.f, 0.f, 0.f, 0.f, 0.f};
  if (jc < NSn) {
    const float (*xb)[8] = (kq < 2) ? bufA : bufB;
    const int kg0 = kq * 128;
    const int koff = (kq < 2) ? kg0 : kg0 - 256;
    #pragma unroll 8
    for (int u = 0; u < 128; ++u) {
      const float v = Ws[(size_t)(kg0 + u) * NSn + jc];
      F4 xa, xb4;
      xa.v = *(const float4*)&xb[koff + u][0];
      xb4.v = *(const float4*)&xb[koff + u][4];
      acc[0] += xa.f[0] * v; acc[1] += xa.f[1] * v;
      acc[2] += xa.f[2] * v; acc[3] += xa.f[3] * v;
      acc[4] += xb4.f[0] * v; acc[5] += xb4.f[1] * v;
      acc[6] += xb4.f[2] * v; acc[7] += xb4.f[3] * v;
    }
  }
  if (kq) {
    #pragma unroll
    for (int i = 0; i < 8; ++i) red[kq - 1][i][jc] = acc[i];
  }
  __syncthreads();
  if (!kq && jc < NSn) {
    #pragma unroll
    for (int i = 0; i < 8; ++i)
      outS[(size_t)(r0 + i) * NSn + jc] =
          acc[i] + red[0][i][jc] + red[1][i][jc] + red[2][i][jc];
  }

  // intent head on blocks 0..15
  if (blk < Bn) {
    const int b = blk;
    if (tid < Sn) aL[tid] = alphas[b * Sn + tid];
    __syncthreads();
    const int h = tid & (Hn - 1);
    const int k2 = tid >> 8;
    float ps = 0.f;
    #pragma unroll 8
    for (int s = k2 * 64; s < k2 * 64 + 64; ++s)
      ps += c_slot[(size_t)(b * Sn + s) * Hn + h] * aL[s];
    ptA[k2][h] = ps;
    __syncthreads();
    if (!k2) {
      cv[h] = c_inte[b * Hn + h] + g2[b * Hn + h] * (ptA[0][h] + ptA[1][h]);
      cv[Hn + h] = hp[(size_t)(b * Sn + Sn - 1) * Hn + h];
    }
    __syncthreads();
    if (tid < NLn * 16) {
      const int l = tid >> 4, c = tid & 15;
      float p = 0.f;
      #pragma unroll
      for (int k = c * 32; k < c * 32 + 32; ++k) p += cv[k] * Wi[k * NLn + l];
      ip[l][c] = p;
    }
    __syncthreads();
    if (tid < NLn) {
      float t = 0.f;
      #pragma unroll
      for (int c = 0; c < 16; ++c) t += ip[tid][c];
      outI[b * NLn + tid] = t;
    }
  }
}

// ---------------------------------------------------------------------------
extern "C" void kernel_launch(void* const* d_in, const int* in_sizes, int n_in,
                              void* d_out, int out_size, void* d_ws, size_t ws_size,
                              hipStream_t stream) {
  const float* hp     = (const float*)d_in[0];
  const float* c_slot = (const float*)d_in[1];
  const float* c_inte = (const float*)d_in[2];
  const float* W_SF   = (const float*)d_in[3];
  const float* V_SF   = (const float*)d_in[4];
  const float* V1     = (const float*)d_in[5];
  const float* V2w    = (const float*)d_in[6];
  const float* V2b    = (const float*)d_in[7];
  const float* wid    = (const float*)d_in[8];
  const float* Wi     = (const float*)d_in[9];
  const float* Ws     = (const float*)d_in[10];
  float* outS = (float*)d_out;                   // B*S*NS
  float* outI = (float*)d_out + Bn * Sn * NSn;   // B*NL

  float* ws = (float*)d_ws;
  float* ZT     = ws;                       // B*H*S (j-contig)
  float* g2     = ZT + (size_t)Bn * Sn * Hn;
  float* alphas = g2 + Bn * Hn;

  // hf + A(it=0) fused
  hipLaunchKernelGGL(k_hfA, dim3(256 + Bn), dim3(1024), 0, stream,
                     hp, V2w, V2b, c_slot, c_inte, W_SF, V_SF, ZT, g2);
  hipLaunchKernelGGL(k_C, dim3(Bn * Sn / 8), dim3(1024), 0, stream,
                     c_slot, V1, g2, ZT, wid, alphas);
  for (int it = 1; it < 3; ++it) {
    hipLaunchKernelGGL(k_A, dim3(Bn), dim3(1024), 0, stream,
                       c_slot, c_inte, W_SF, V_SF, alphas, g2);
    hipLaunchKernelGGL(k_C, dim3(Bn * Sn / 8), dim3(1024), 0, stream,
                       c_slot, V1, g2, ZT, wid, alphas);
  }
  hipLaunchKernelGGL(k_out, dim3(Bn * Sn / 8), dim3(512), 0, stream,
                     hp, c_slot, c_inte, g2, alphas, Wi, Ws, outS, outI);
}

// Round 18
// 94.388 us; speedup vs baseline: 1.3991x; 1.0252x over previous
//
#include <hip/hip_runtime.h>

#define Bn 16
#define Sn 128
#define Hn 256
#define NLn 22
#define NSn 122

#define K2c 2.8853900817779268f   // 2*log2(e)
#define L2Ec 1.4426950408889634f  // log2(e)

__device__ __forceinline__ float fexp2(float x) { return __builtin_amdgcn_exp2f(x); }
__device__ __forceinline__ float frcp(float x) { return __builtin_amdgcn_rcpf(x); }

union F4 { float4 v; float f[4]; };

// ---------------------------------------------------------------------------
// A-update body: rL -> m -> em -> f -> g2.  1024 threads = h(256) x kq(4).
// Writes g2[b][h] directly.  use_alpha=0 for iteration 0.
// ---------------------------------------------------------------------------
__device__ __forceinline__ void A_body(const float* __restrict__ c_slot,
                                       const float* __restrict__ c_inte,
                                       const float* __restrict__ W_SF,
                                       const float* __restrict__ V_SF,
                                       const float* __restrict__ alphas,
                                       float* __restrict__ g2,
                                       int b, int use_alpha,
                                       float* rL, float* fLq, float* aL,
                                       float (*pt)[Hn]) {
  const int tid = threadIdx.x;
  const int h = tid & (Hn - 1);
  const int kq = tid >> 8;

  if (use_alpha) {
    if (tid < Sn) aL[tid] = alphas[b * Sn + tid];
    __syncthreads();
    float ps = 0.f;
    #pragma unroll 8
    for (int s = kq * 32; s < kq * 32 + 32; ++s)
      ps += c_slot[(size_t)(b * Sn + s) * Hn + h] * aL[s];
    pt[kq][h] = ps;
    __syncthreads();
    if (!kq)
      rL[h] = c_inte[b * Hn + h] +
              g2[b * Hn + h] * (pt[0][h] + pt[1][h] + pt[2][h] + pt[3][h]);
  } else {
    if (!kq) rL[h] = c_inte[b * Hn + h];
  }
  __syncthreads();

  // m = rL @ W_SF (4-way k-split)
  float pm = 0.f;
  #pragma unroll 8
  for (int k = kq * 64; k < kq * 64 + 64; ++k)
    pm += rL[k] * W_SF[(size_t)k * Hn + h];
  __syncthreads();               // protect pt from rs-phase reads
  pt[kq][h] = pm;
  __syncthreads();
  const float m = pt[0][h] + pt[1][h] + pt[2][h] + pt[3][h];
  const float em = fexp2(fminf(fmaxf(K2c * m, -60.f), 60.f));

  // f partial: 32 s per kq
  float pr = 0.f;
  #pragma unroll 8
  for (int s = kq * 32; s < kq * 32 + 32; ++s) {
    float zc = fminf(fmaxf(K2c * c_slot[(size_t)(b * Sn + s) * Hn + h], -60.f), 60.f);
    pr += frcp(fmaf(fexp2(zc), em, 1.f));
  }
  __syncthreads();               // all m-reads of pt complete
  pt[kq][h] = pr;
  __syncthreads();
  if (!kq) fLq[h] = (float)Sn - 2.f * (pt[0][h] + pt[1][h] + pt[2][h] + pt[3][h]);
  __syncthreads();

  // g2 = fLq @ V_SF (4-way k-split)
  float pg = 0.f;
  #pragma unroll 8
  for (int k = kq * 64; k < kq * 64 + 64; ++k)
    pg += fLq[k] * V_SF[(size_t)k * Hn + h];
  __syncthreads();
  pt[kq][h] = pg;
  __syncthreads();
  if (!kq)
    g2[b * Hn + h] = pt[0][h] + pt[1][h] + pt[2][h] + pt[3][h];
}

// ---------------------------------------------------------------------------
// k_hfA: blocks 0..255: hf -> ZT (8 rows each, j-contiguous exp2(K2*hf)).
//        blocks 256..271: A-update for iteration 0 (no alphas) -> g2.
// ---------------------------------------------------------------------------
__global__ __launch_bounds__(1024) void k_hfA(const float* __restrict__ hp,
                                              const float* __restrict__ V2w,
                                              const float* __restrict__ V2b,
                                              const float* __restrict__ c_slot,
                                              const float* __restrict__ c_inte,
                                              const float* __restrict__ W_SF,
                                              const float* __restrict__ V_SF,
                                              float* __restrict__ ZT,
                                              float* __restrict__ g2) {
  __shared__ float xT[Hn][8];
  __shared__ float pp[3][Hn][8];
  __shared__ float rL[Hn];
  __shared__ float fLq[Hn];
  __shared__ float aL[Sn];
  __shared__ float pt[4][Hn];
  const int tid = threadIdx.x;
  const int blk = blockIdx.x;

  if (blk >= 256) {              // A-update, iteration 0
    A_body(c_slot, c_inte, W_SF, V_SF, nullptr, g2, blk - 256, 0,
           rL, fLq, aL, pt);
    return;
  }

  const int r0 = blk * 8;
  const int b = r0 >> 7;
  const int j0 = r0 & (Sn - 1);
  const int h = tid & (Hn - 1);
  const int kh = tid >> 8;       // 0..3
  xT[h][kh * 2]     = hp[(size_t)(r0 + kh * 2) * Hn + h];
  xT[h][kh * 2 + 1] = hp[(size_t)(r0 + kh * 2 + 1) * Hn + h];
  __syncthreads();
  float acc[8] = {0.f, 0.f, 0.f, 0.f, 0.f, 0.f, 0.f, 0.f};
  #pragma unroll 8
  for (int k = kh * 64; k < kh * 64 + 64; ++k) {
    const float v = V2w[(size_t)k * Hn + h];
    F4 xa, xb;
    xa.v = *(const float4*)&xT[k][0];
    xb.v = *(const float4*)&xT[k][4];
    acc[0] += xa.f[0] * v; acc[1] += xa.f[1] * v;
    acc[2] += xa.f[2] * v; acc[3] += xa.f[3] * v;
    acc[4] += xb.f[0] * v; acc[5] += xb.f[1] * v;
    acc[6] += xb.f[2] * v; acc[7] += xb.f[3] * v;
  }
  if (kh) {
    F4 s0, s1;
    s0.f[0] = acc[0]; s0.f[1] = acc[1]; s0.f[2] = acc[2]; s0.f[3] = acc[3];
    s1.f[0] = acc[4]; s1.f[1] = acc[5]; s1.f[2] = acc[6]; s1.f[3] = acc[7];
    *(float4*)&pp[kh - 1][h][0] = s0.v;
    *(float4*)&pp[kh - 1][h][4] = s1.v;
  }
  __syncthreads();
  if (!kh) {
    const float bj = V2b[h];
    F4 o0, o1;
    #pragma unroll
    for (int i = 0; i < 8; ++i) {
      float z = K2c * (acc[i] + pp[0][h][i] + pp[1][h][i] + pp[2][h][i] + bj);
      z = fminf(fmaxf(z, -60.f), 60.f);
      if (i < 4) o0.f[i] = fexp2(z); else o1.f[i - 4] = fexp2(z);
    }
    *(float4*)&ZT[((size_t)b * Hn + h) * Sn + j0] = o0.v;
    *(float4*)&ZT[((size_t)b * Hn + h) * Sn + j0 + 4] = o1.v;
  }
}

// ---------------------------------------------------------------------------
// k_A: iterations 1,2. 16 blocks (one per b) x 1024 threads. Writes g2.
// ---------------------------------------------------------------------------
__global__ __launch_bounds__(1024) void k_A(const float* __restrict__ c_slot,
                                            const float* __restrict__ c_inte,
                                            const float* __restrict__ W_SF,
                                            const float* __restrict__ V_SF,
                                            const float* __restrict__ alphas,
                                            float* __restrict__ g2) {
  __shared__ float rL[Hn];
  __shared__ float fLq[Hn];
  __shared__ float aL[Sn];
  __shared__ float pt[4][Hn];
  A_body(c_slot, c_inte, W_SF, V_SF, alphas, g2, blockIdx.x, 1,
         rL, fLq, aL, pt);
}

// ---------------------------------------------------------------------------
// k_C: scores. 256 blocks = (b, 8-row group), 1024 threads, ~49KB LDS.
// T1 XCD mapping: b = blk & 15 (same-b blocks share an XCD L2).
// Phase3 uses PAIRED-RCP: w1/(1+t1)+w2/(1+t2) =
//   [w1(1+t2)+w2(1+t1)] * rcp((1+t1)(1+t2))  — halves trans-pipe ops.
//   (P=inf only when both terms are ~2^-60: rcp(inf)=0 is then correct.)
// ---------------------------------------------------------------------------
__global__ __launch_bounds__(1024) void k_C(const float* __restrict__ c_slot,
                                            const float* __restrict__ V1,
                                            const float* __restrict__ g2,
                                            const float* __restrict__ ZT,
                                            const float* __restrict__ wid,
                                            float* __restrict__ alphas) {
  __shared__ float bufA[Hn][8];    // xT
  __shared__ float bufB[Hn][8];    // YT
  __shared__ union {
    float pp[3][Hn][8];            // phase2 partials (24KB)
    float red[7][8][Sn];           // phase3 partials (28KB)
  } u;
  __shared__ float sc8[8][Sn];
  __shared__ float wL[Hn];

  const int tid = threadIdx.x;
  const int blk = blockIdx.x;
  const int b = blk & 15;          // T1: same-b blocks -> same XCD
  const int i0 = (blk >> 4) * 8;
  const int h = tid & (Hn - 1);
  const int kq = tid >> 8;         // 0..3

  // phase1: 2 rows per thread
  {
    const float gv = g2[b * Hn + h];
    const int ii = kq * 2;
    bufA[h][ii]     = gv * c_slot[(size_t)(b * Sn + i0 + ii) * Hn + h];
    bufA[h][ii + 1] = gv * c_slot[(size_t)(b * Sn + i0 + ii + 1) * Hn + h];
    if (tid < Hn) wL[tid] = wid[tid];
  }
  __syncthreads();

  // phase2: sf = x @ V1 (4-way kq split) -> Y
  {
    float acc[8] = {0.f, 0.f, 0.f, 0.f, 0.f, 0.f, 0.f, 0.f};
    #pragma unroll 8
    for (int k = kq * 64; k < kq * 64 + 64; ++k) {
      const float v = V1[(size_t)k * Hn + h];
      F4 xa, xb;
      xa.v = *(const float4*)&bufA[k][0];
      xb.v = *(const float4*)&bufA[k][4];
      acc[0] += xa.f[0] * v; acc[1] += xa.f[1] * v;
      acc[2] += xa.f[2] * v; acc[3] += xa.f[3] * v;
      acc[4] += xb.f[0] * v; acc[5] += xb.f[1] * v;
      acc[6] += xb.f[2] * v; acc[7] += xb.f[3] * v;
    }
    if (kq) {
      F4 s0, s1;
      s0.f[0] = acc[0]; s0.f[1] = acc[1]; s0.f[2] = acc[2]; s0.f[3] = acc[3];
      s1.f[0] = acc[4]; s1.f[1] = acc[5]; s1.f[2] = acc[6]; s1.f[3] = acc[7];
      *(float4*)&u.pp[kq - 1][h][0] = s0.v;
      *(float4*)&u.pp[kq - 1][h][4] = s1.v;
    }
    __syncthreads();
    if (!kq) {
      #pragma unroll
      for (int i = 0; i < 8; ++i) {
        float z = K2c * (acc[i] + u.pp[0][h][i] + u.pp[1][h][i] + u.pp[2][h][i]);
        z = fminf(fmaxf(z, -60.f), 60.f);
        bufB[h][i] = fexp2(z);
      }
    }
  }
  __syncthreads();

  // phase3: paired-rcp einsum (lane = j), 16 hh-pairs per thread
  const int j = tid & (Sn - 1);
  const int hq = tid >> 7;         // 0..7
  float a8[8] = {0.f, 0.f, 0.f, 0.f, 0.f, 0.f, 0.f, 0.f};
  const float* zp = ZT + ((size_t)b * Hn + hq * 32) * Sn + j;
  #pragma unroll 2
  for (int hh = 0; hh < 32; hh += 2) {
    const float z1 = zp[(size_t)hh * Sn];
    const float z2 = zp[(size_t)(hh + 1) * Sn];
    const float w1 = wL[hq * 32 + hh];
    const float w2 = wL[hq * 32 + hh + 1];
    F4 ya1, yb1, ya2, yb2;
    ya1.v = *(const float4*)&bufB[hq * 32 + hh][0];
    yb1.v = *(const float4*)&bufB[hq * 32 + hh][4];
    ya2.v = *(const float4*)&bufB[hq * 32 + hh + 1][0];
    yb2.v = *(const float4*)&bufB[hq * 32 + hh + 1][4];
    #pragma unroll
    for (int i = 0; i < 4; ++i) {
      {
        const float A = fmaf(ya1.f[i], z1, 1.f);
        const float B = fmaf(ya2.f[i], z2, 1.f);
        const float N = fmaf(w1, B, w2 * A);
        a8[i] = fmaf(N, frcp(A * B), a8[i]);
      }
      {
        const float A = fmaf(yb1.f[i], z1, 1.f);
        const float B = fmaf(yb2.f[i], z2, 1.f);
        const float N = fmaf(w1, B, w2 * A);
        a8[4 + i] = fmaf(N, frcp(A * B), a8[4 + i]);
      }
    }
  }
  if (hq) {
    #pragma unroll
    for (int i = 0; i < 8; ++i) u.red[hq - 1][i][j] = a8[i];
  }
  __syncthreads();
  if (!hq) {
    #pragma unroll
    for (int i = 0; i < 8; ++i) {
      float tot = a8[i];
      #pragma unroll
      for (int r = 0; r < 7; ++r) tot += u.red[r][i][j];
      sc8[i][j] = -2.f * L2Ec * tot;   // log2-domain score (const dropped)
    }
  }
  __syncthreads();

  // phase4: softmax, 8 rows x 32 lanes
  if (tid < 256) {
    const int row = tid >> 5;
    const int l5 = tid & 31;
    const float v0 = sc8[row][l5];
    const float v1 = sc8[row][l5 + 32];
    const float v2 = sc8[row][l5 + 64];
    const float v3 = sc8[row][l5 + 96];
    float mx = fmaxf(fmaxf(v0, v1), fmaxf(v2, v3));
    #pragma unroll
    for (int o = 16; o >= 1; o >>= 1) mx = fmaxf(mx, __shfl_xor(mx, o, 32));
    float sm = fexp2(v0 - mx) + fexp2(v1 - mx) + fexp2(v2 - mx) + fexp2(v3 - mx);
    #pragma unroll
    for (int o = 16; o >= 1; o >>= 1) sm += __shfl_xor(sm, o, 32);
    if (l5 == 0) {
      const int ig = i0 + row;
      alphas[b * Sn + ig] = fexp2(sc8[row][ig] - mx) * frcp(sm);
    }
  }
}

// ---------------------------------------------------------------------------
// k_out: 256 blocks x 512. All blocks: slot head (8 rows). Blocks 0..15 also
// do the intent head afterwards (disjoint LDS arrays).
// ---------------------------------------------------------------------------
__global__ __launch_bounds__(512) void k_out(const float* __restrict__ hp,
                                             const float* __restrict__ c_slot,
                                             const float* __restrict__ c_inte,
                                             const float* __restrict__ g2,
                                             const float* __restrict__ alphas,
                                             const float* __restrict__ Wi,
                                             const float* __restrict__ Ws,
                                             float* __restrict__ outS,
                                             float* __restrict__ outI) {
  __shared__ float bufA[Hn][8];
  __shared__ float bufB[Hn][8];
  __shared__ float red[3][8][Sn];
  __shared__ float aL[Sn];
  __shared__ float cv[2 * Hn];
  __shared__ float ptA[2][Hn];
  __shared__ float ip[NLn][16];
  const int tid = threadIdx.x;
  const int blk = blockIdx.x;
  const int r0 = blk * 8;
  const int b2 = r0 >> 7;

  if (tid < Hn) {
    #pragma unroll
    for (int i = 0; i < 8; ++i) bufA[tid][i] = hp[(size_t)(r0 + i) * Hn + tid];
  } else {
    const int t = tid - Hn;
    const float gv = g2[b2 * Hn + t];
    #pragma unroll
    for (int i = 0; i < 8; ++i)
      bufB[t][i] = gv * c_slot[(size_t)(r0 + i) * Hn + t];
  }
  __syncthreads();
  const int jc = tid & 127;
  const int kq = tid >> 7;
  float acc[8] = {0.f, 0.f, 0.f, 0.f, 0.f, 0.f, 0.f, 0.f};
  if (jc < NSn) {
    const float (*xb)[8] = (kq < 2) ? bufA : bufB;
    const int kg0 = kq * 128;
    const int koff = (kq < 2) ? kg0 : kg0 - 256;
    #pragma unroll 8
    for (int u = 0; u < 128; ++u) {
      const float v = Ws[(size_t)(kg0 + u) * NSn + jc];
      F4 xa, xb4;
      xa.v = *(const float4*)&xb[koff + u][0];
      xb4.v = *(const float4*)&xb[koff + u][4];
      acc[0] += xa.f[0] * v; acc[1] += xa.f[1] * v;
      acc[2] += xa.f[2] * v; acc[3] += xa.f[3] * v;
      acc[4] += xb4.f[0] * v; acc[5] += xb4.f[1] * v;
      acc[6] += xb4.f[2] * v; acc[7] += xb4.f[3] * v;
    }
  }
  if (kq) {
    #pragma unroll
    for (int i = 0; i < 8; ++i) red[kq - 1][i][jc] = acc[i];
  }
  __syncthreads();
  if (!kq && jc < NSn) {
    #pragma unroll
    for (int i = 0; i < 8; ++i)
      outS[(size_t)(r0 + i) * NSn + jc] =
          acc[i] + red[0][i][jc] + red[1][i][jc] + red[2][i][jc];
  }

  // intent head on blocks 0..15
  if (blk < Bn) {
    const int b = blk;
    if (tid < Sn) aL[tid] = alphas[b * Sn + tid];
    __syncthreads();
    const int h = tid & (Hn - 1);
    const int k2 = tid >> 8;
    float ps = 0.f;
    #pragma unroll 8
    for (int s = k2 * 64; s < k2 * 64 + 64; ++s)
      ps += c_slot[(size_t)(b * Sn + s) * Hn + h] * aL[s];
    ptA[k2][h] = ps;
    __syncthreads();
    if (!k2) {
      cv[h] = c_inte[b * Hn + h] + g2[b * Hn + h] * (ptA[0][h] + ptA[1][h]);
      cv[Hn + h] = hp[(size_t)(b * Sn + Sn - 1) * Hn + h];
    }
    __syncthreads();
    if (tid < NLn * 16) {
      const int l = tid >> 4, c = tid & 15;
      float p = 0.f;
      #pragma unroll
      for (int k = c * 32; k < c * 32 + 32; ++k) p += cv[k] * Wi[k * NLn + l];
      ip[l][c] = p;
    }
    __syncthreads();
    if (tid < NLn) {
      float t = 0.f;
      #pragma unroll
      for (int c = 0; c < 16; ++c) t += ip[tid][c];
      outI[b * NLn + tid] = t;
    }
  }
}

// ---------------------------------------------------------------------------
extern "C" void kernel_launch(void* const* d_in, const int* in_sizes, int n_in,
                              void* d_out, int out_size, void* d_ws, size_t ws_size,
                              hipStream_t stream) {
  const float* hp     = (const float*)d_in[0];
  const float* c_slot = (const float*)d_in[1];
  const float* c_inte = (const float*)d_in[2];
  const float* W_SF   = (const float*)d_in[3];
  const float* V_SF   = (const float*)d_in[4];
  const float* V1     = (const float*)d_in[5];
  const float* V2w    = (const float*)d_in[6];
  const float* V2b    = (const float*)d_in[7];
  const float* wid    = (const float*)d_in[8];
  const float* Wi     = (const float*)d_in[9];
  const float* Ws     = (const float*)d_in[10];
  float* outS = (float*)d_out;                   // B*S*NS
  float* outI = (float*)d_out + Bn * Sn * NSn;   // B*NL

  float* ws = (float*)d_ws;
  float* ZT     = ws;                       // B*H*S (j-contig)
  float* g2     = ZT + (size_t)Bn * Sn * Hn;
  float* alphas = g2 + Bn * Hn;

  // hf + A(it=0) fused
  hipLaunchKernelGGL(k_hfA, dim3(256 + Bn), dim3(1024), 0, stream,
                     hp, V2w, V2b, c_slot, c_inte, W_SF, V_SF, ZT, g2);
  hipLaunchKernelGGL(k_C, dim3(Bn * Sn / 8), dim3(1024), 0, stream,
                     c_slot, V1, g2, ZT, wid, alphas);
  for (int it = 1; it < 3; ++it) {
    hipLaunchKernelGGL(k_A, dim3(Bn), dim3(1024), 0, stream,
                       c_slot, c_inte, W_SF, V_SF, alphas, g2);
    hipLaunchKernelGGL(k_C, dim3(Bn * Sn / 8), dim3(1024), 0, stream,
                       c_slot, V1, g2, ZT, wid, alphas);
  }
  hipLaunchKernelGGL(k_out, dim3(Bn * Sn / 8), dim3(512), 0, stream,
                     hp, c_slot, c_inte, g2, alphas, Wi, Ws, outS, outI);
}